// Round 11
// baseline (662.941 us; speedup 1.0000x reference)
//
#include <hip/hip_runtime.h>
#include <cstdint>
#include <cstddef>

// Problem constants
#define N0c 30000
#define F0c 128
#define Hc  256
#define Cc  16
#define N1c 3000
#define Bc  16
#define E0c 960000
#define E1c 48000
#define NALL 33000            // N0 + N1 (concatenated graphs)
#define EALL 1008000          // E0 + E1
#define EPSc 1e-5f

static __host__ __device__ inline int cdiv_i(int a, int b) { return (a + b - 1) / b; }

// round-to-nearest-even fp32 -> bf16 (returns the 16 bf16 bits)
static __device__ inline unsigned short bfbits(float f) {
    unsigned u = __float_as_uint(f);
    return (unsigned short)((u + 0x7fffu + ((u >> 16) & 1u)) >> 16);
}

typedef short short8 __attribute__((ext_vector_type(8)));   // 8 bf16 = 4 VGPRs
typedef float floatx4 __attribute__((ext_vector_type(4)));

// ---------------- graph preprocessing (both graphs concatenated) ----------------

__global__ void count_deg_all(const int* __restrict__ dst0, const int* __restrict__ dst1,
                              int* __restrict__ deg) {
    int e = blockIdx.x * blockDim.x + threadIdx.x;
    if (e < E0c) atomicAdd(&deg[dst0[e]], 1);
    else if (e < EALL) atomicAdd(&deg[N0c + dst1[e - E0c]], 1);
}

// scan + dinv fused: dinv[i] = rsqrt(deg[i]+1)
__global__ void scan_block(const int* __restrict__ cnt, int n, int* __restrict__ rp,
                           int* __restrict__ blkSum, float* __restrict__ dinv) {
    __shared__ int sh[256];
    int t = threadIdx.x;
    int i = blockIdx.x * 256 + t;
    int v = (i < n) ? cnt[i] : 0;
    if (i < n) dinv[i] = rsqrtf((float)(v + 1));
    sh[t] = v; __syncthreads();
    for (int off = 1; off < 256; off <<= 1) {
        int add = (t >= off) ? sh[t - off] : 0;
        __syncthreads();
        sh[t] += add;
        __syncthreads();
    }
    if (i < n) rp[i] = sh[t] - v;
    if (t == 255) blkSum[blockIdx.x] = sh[255];
}

__global__ void scan_sums(const int* __restrict__ blkSum, int nb, int* __restrict__ blkOff,
                          int* __restrict__ rp, int n) {
    __shared__ int sh[256];
    int t = threadIdx.x;
    int v = (t < nb) ? blkSum[t] : 0;
    sh[t] = v; __syncthreads();
    for (int off = 1; off < 256; off <<= 1) {
        int add = (t >= off) ? sh[t - off] : 0;
        __syncthreads();
        sh[t] += add;
        __syncthreads();
    }
    blkOff[t] = sh[t] - v;
    if (t == 255) rp[n] = sh[255];
}

// ---------------- mega-prep: all post-scan independent work in ONE kernel ------
#define NB_FILL 3938
#define NB_RPF  129
#define NB_CVT  3750
#define NB_PW   386
#define NB_SEG  118

__global__ void megaprep(const int* __restrict__ src0, const int* __restrict__ dst0,
                         const int* __restrict__ src1, const int* __restrict__ dst1,
                         const int* __restrict__ rp, const int* __restrict__ blkOff,
                         int* __restrict__ tmp, const float* __restrict__ dinv,
                         unsigned* __restrict__ csw, int* __restrict__ rpf,
                         const float* __restrict__ x, unsigned short* __restrict__ xbf,
                         const float* __restrict__ W_in0, const float* __restrict__ W_h0,
                         const float* __restrict__ b0, const float* __restrict__ g0,
                         const float* __restrict__ be0, const float* __restrict__ m0,
                         const float* __restrict__ v0,
                         unsigned short* __restrict__ Wt0, unsigned short* __restrict__ Wt1,
                         float* __restrict__ sc0, float* __restrict__ sh0,
                         float* __restrict__ sc1, float* __restrict__ sh1,
                         const int* __restrict__ pool1, int* __restrict__ start0) {
    int bx = blockIdx.x, t = threadIdx.x;
    if (bx < NB_FILL) {
        int e = bx * 256 + t;
        if (e >= EALL) return;
        int s, d;
        if (e < E0c) { s = src0[e]; d = dst0[e]; }
        else         { s = N0c + src1[e - E0c]; d = N0c + dst1[e - E0c]; }
        int pos = rp[d] + blkOff[d >> 8] + atomicAdd(&tmp[d], 1);
        float w = dinv[s] * dinv[d];
        int sloc = (e < E0c) ? s : (s - N0c);
        csw[pos] = ((unsigned)bfbits(w) << 16) | (unsigned)sloc;
    } else if (bx < NB_FILL + NB_RPF) {
        int i = (bx - NB_FILL) * 256 + t;
        if (i < NALL) rpf[i] = rp[i] + blkOff[i >> 8];
        else if (i == NALL) rpf[NALL] = rp[NALL];   // total (already final)
    } else if (bx < NB_FILL + NB_RPF + NB_CVT) {
        int i = (bx - NB_FILL - NB_RPF) * 256 + t;  // float4 index
        if (i >= N0c * 32) return;
        float4 v = ((const float4*)x)[i];
        ushort4 o;
        o.x = bfbits(v.x); o.y = bfbits(v.y); o.z = bfbits(v.z); o.w = bfbits(v.w);
        ((ushort4*)xbf)[i] = o;
    } else if (bx < NB_FILL + NB_RPF + NB_CVT + NB_PW) {
        int pb = bx - NB_FILL - NB_RPF - NB_CVT;
        if (pb < 128) {
            int i = pb * 256 + t;
            int k = i >> 8, col = i & 255;
            Wt0[col * 128 + k] = bfbits(W_in0[i]);
        } else if (pb < 384) {
            int i = (pb - 128) * 256 + t;
            int k = i >> 8, col = i & 255;
            Wt1[col * 256 + k] = bfbits(W_h0[i]);
        } else if (pb == 384) {
            float s = g0[t] * rsqrtf(v0[t] + EPSc);
            sc0[t] = s;
            sh0[t] = (b0[t] - m0[t]) * s + be0[t];
        } else {
            int tt = t + 256;
            float s = g0[tt] * rsqrtf(v0[tt] + EPSc);
            sc1[t] = s;
            sh1[t] = (b0[tt] - m0[tt]) * s + be0[tt];
        }
    } else {
        int i = (bx - NB_FILL - NB_RPF - NB_CVT - NB_PW) * 256 + t;
        if (i > N0c) return;
        if (i == 0) {
            for (int c = 0; c <= pool1[0]; ++c) start0[c] = 0;
        } else if (i == N0c) {
            for (int c = pool1[N0c - 1] + 1; c <= N1c; ++c) start0[c] = N0c;
        } else {
            int a = pool1[i - 1], b = pool1[i];
            for (int c = a + 1; c <= b; ++c) start0[c] = i;
        }
    }
}

// ---------------- aggregation (bf16 gather, fp32 accumulate) ----------------

static __device__ inline void acc8(float a[8], float w, uint4 v) {
    a[0] += w * __uint_as_float(v.x << 16);
    a[1] += w * __uint_as_float(v.x & 0xffff0000u);
    a[2] += w * __uint_as_float(v.y << 16);
    a[3] += w * __uint_as_float(v.y & 0xffff0000u);
    a[4] += w * __uint_as_float(v.z << 16);
    a[5] += w * __uint_as_float(v.z & 0xffff0000u);
    a[6] += w * __uint_as_float(v.w << 16);
    a[7] += w * __uint_as_float(v.w & 0xffff0000u);
}

// RSU: bf16 row stride in 16B units (16 for 128-wide, 32 for 256-wide).
// NCHUNK chunks of 64 cols; chunk = blockIdx&(NCHUNK-1) pins chunks to XCD sets.
// 32-bit gather addressing; wave-uniform trip count + unroll-by-2 ILP.
// OBF16: write bf16 rows (feeds MFMA) else fp32 rows. NO atomics anywhere.
template <int RSU, int NCHUNK, bool OBF16>
__global__ __launch_bounds__(256) void agg_bf16(
    const unsigned short* __restrict__ x, const int* __restrict__ rp,
    const unsigned* __restrict__ csw, const float* __restrict__ dinv,
    void* __restrict__ zv, int N) {
    constexpr int SHIFT = (RSU == 32) ? 9 : 8;   // log2(row bytes)
    int b = blockIdx.x;
    int chunk = b & (NCHUNK - 1);
    int node = (b / NCHUNK) * 4 + (threadIdx.x >> 6);
    if (node >= N) return;
    int lane = threadIdx.x & 63;
    int par = lane >> 3;
    int cl = lane & 7;
    int c4 = chunk * 8 + cl;             // uint4 index within bf16 row
    const char* xb = (const char*)x;
    unsigned coff = (unsigned)c4 << 4;   // byte offset of this lane's 16B slice
    float a[8] = {0.f, 0.f, 0.f, 0.f, 0.f, 0.f, 0.f, 0.f};
    if (par == 0) {                      // self-loop term exactly once
        float di = dinv[node];
        uint4 v = *(const uint4*)(xb + (((unsigned)node << SHIFT) + coff));
        acc8(a, di * di, v);
    }
    int e0 = rp[node], e1 = rp[node + 1];
    for (int base = e0; base < e1; base += 64) {
        int batch = e1 - base;
        if (batch > 64) batch = 64;
        unsigned my = 0;
        if (lane < batch) my = csw[base + lane];   // up to 64 edges in ONE load
        int full = batch >> 3;                      // wave-uniform trip count
        int i = 0;
        for (; i + 1 < full; i += 2) {              // 2 gathers in flight
            unsigned ew0 = (unsigned)__shfl((int)my, i * 8 + par, 64);
            unsigned ew1 = (unsigned)__shfl((int)my, i * 8 + 8 + par, 64);
            uint4 v0 = *(const uint4*)(xb + (((ew0 & 0xffffu) << SHIFT) + coff));
            uint4 v1 = *(const uint4*)(xb + (((ew1 & 0xffffu) << SHIFT) + coff));
            acc8(a, __uint_as_float(ew0 & 0xffff0000u), v0);
            acc8(a, __uint_as_float(ew1 & 0xffff0000u), v1);
        }
        if (i < full) {
            unsigned ew = (unsigned)__shfl((int)my, i * 8 + par, 64);
            uint4 v = *(const uint4*)(xb + (((ew & 0xffffu) << SHIFT) + coff));
            acc8(a, __uint_as_float(ew & 0xffff0000u), v);
        }
        int rem = batch & 7;
        if (rem) {                                  // single guarded tail step
            unsigned ew = (unsigned)__shfl((int)my, full * 8 + par, 64);
            if (par < rem) {
                unsigned off = ((ew & 0xffffu) << SHIFT) + coff;
                float w = __uint_as_float(ew & 0xffff0000u);
                uint4 v = *(const uint4*)(xb + off);
                acc8(a, w, v);
            }
        }
    }
#pragma unroll
    for (int m = 8; m < 64; m <<= 1) {
#pragma unroll
        for (int k = 0; k < 8; ++k) a[k] += __shfl_xor(a[k], m, 64);
    }
    if (par == 0) {
        if (OBF16) {
            uint4 o;
            o.x = (unsigned)bfbits(a[0]) | ((unsigned)bfbits(a[1]) << 16);
            o.y = (unsigned)bfbits(a[2]) | ((unsigned)bfbits(a[3]) << 16);
            o.z = (unsigned)bfbits(a[4]) | ((unsigned)bfbits(a[5]) << 16);
            o.w = (unsigned)bfbits(a[6]) | ((unsigned)bfbits(a[7]) << 16);
            ((uint4*)zv)[(size_t)node * RSU + c4] = o;
        } else {
            float4* zp = (float4*)zv + (size_t)node * (RSU * 2) + c4 * 2;
            zp[0] = make_float4(a[0], a[1], a[2], a[3]);
            zp[1] = make_float4(a[4], a[5], a[6], a[7]);
        }
    }
}

// ---------------- MFMA bf16 GEMM: (M x K)bf16 @ Wt(256 x K)bf16 -> bf16 out ----

template <int K>
__global__ __launch_bounds__(256) void gemm_mfma_bn(
    const unsigned short* __restrict__ A, const unsigned short* __restrict__ Wt,
    const float* __restrict__ sc, const float* __restrict__ sh,
    unsigned short* __restrict__ out, int M) {
    constexpr int LDS_S = 40;
    __shared__ unsigned short As[64 * LDS_S];
    __shared__ unsigned short Bs[256 * LDS_S];
    int tid = threadIdx.x;
    int w = tid >> 6, l = tid & 63;
    int quad = l >> 4, lm = l & 15;
    int row0 = blockIdx.x * 64;
    floatx4 acc[4][4];
#pragma unroll
    for (int i = 0; i < 4; ++i)
#pragma unroll
        for (int j = 0; j < 4; ++j) acc[i][j] = (floatx4){0.f, 0.f, 0.f, 0.f};

    int ar = tid >> 2;          // A staging: row 0..63
    int ac = (tid & 3) * 8;     // short offset 0,8,16,24

    for (int k0 = 0; k0 < K; k0 += 32) {
        uint4 av = make_uint4(0, 0, 0, 0);
        if (row0 + ar < M) av = *(const uint4*)(A + (size_t)(row0 + ar) * K + k0 + ac);
        *(uint4*)&As[ar * LDS_S + ac] = av;
#pragma unroll
        for (int c = 0; c < 4; ++c) {    // Bs: thread -> col tid, 4 k-chunks
            uint4 bv = *(const uint4*)(Wt + (size_t)tid * K + k0 + c * 8);
            *(uint4*)&Bs[tid * LDS_S + c * 8] = bv;
        }
        __syncthreads();
        short8 af[4], bf[4];
#pragma unroll
        for (int i = 0; i < 4; ++i)
            af[i] = *(const short8*)&As[(i * 16 + lm) * LDS_S + quad * 8];
#pragma unroll
        for (int j = 0; j < 4; ++j)
            bf[j] = *(const short8*)&Bs[(w * 64 + j * 16 + lm) * LDS_S + quad * 8];
#pragma unroll
        for (int i = 0; i < 4; ++i)
#pragma unroll
            for (int j = 0; j < 4; ++j)
                acc[i][j] = __builtin_amdgcn_mfma_f32_16x16x32_bf16(af[i], bf[j], acc[i][j], 0, 0, 0);
        __syncthreads();
    }
    // epilogue: C/D map col=lane&15, row=quad*4+reg [verified m89/m91]
#pragma unroll
    for (int j = 0; j < 4; ++j) {
        int col = w * 64 + j * 16 + lm;
        float s = sc[col], h = sh[col];
#pragma unroll
        for (int i = 0; i < 4; ++i) {
            int rb = row0 + i * 16 + quad * 4;
#pragma unroll
            for (int r = 0; r < 4; ++r) {
                int row = rb + r;
                if (row < M) {
                    float v = acc[i][j][r] * s + h;
                    v = fmaxf(v, 0.f);
                    out[(size_t)row * 256 + col] = bfbits(v);
                }
            }
        }
    }
}

// ---------------- fp32 vector GEMM (kept for small M=3000, precision-critical) --

template <int K, bool RELU, bool ZEROEMPTY, bool OBF16>
__global__ __launch_bounds__(256) void gemm_bn(
    const float* __restrict__ A, const float* __restrict__ W,
    const float* __restrict__ bias, const float* __restrict__ gam,
    const float* __restrict__ bet, const float* __restrict__ mu,
    const float* __restrict__ var, const int* __restrict__ cnt,
    void* __restrict__ outv, int M) {
    __shared__ __align__(16) float As[16][64];
    __shared__ __align__(16) float Bs[16][64];
    int tid = threadIdx.x;
    int tm = tid >> 4, tn = tid & 15;
    int row0 = blockIdx.x * 64, col0 = blockIdx.y * 64;
    float acc[4][4] = {};
    int ar = tid >> 2;
    int ak = (tid & 3) * 4;
    int bk = tid >> 4;
    int bn = (tid & 15) * 4;

    for (int kk = 0; kk < K; kk += 16) {
        float4 av = make_float4(0.f, 0.f, 0.f, 0.f);
        int grow = row0 + ar;
        if (grow < M) av = *(const float4*)(A + (size_t)grow * K + kk + ak);
        As[ak + 0][ar] = av.x;
        As[ak + 1][ar] = av.y;
        As[ak + 2][ar] = av.z;
        As[ak + 3][ar] = av.w;
        float4 bv = *(const float4*)(W + (size_t)(kk + bk) * 256 + col0 + bn);
        *(float4*)&Bs[bk][bn] = bv;
        __syncthreads();
#pragma unroll
        for (int k = 0; k < 16; ++k) {
            float4 a = *(const float4*)&As[k][tm * 4];
            float4 b = *(const float4*)&Bs[k][tn * 4];
            acc[0][0] += a.x * b.x; acc[0][1] += a.x * b.y; acc[0][2] += a.x * b.z; acc[0][3] += a.x * b.w;
            acc[1][0] += a.y * b.x; acc[1][1] += a.y * b.y; acc[1][2] += a.y * b.z; acc[1][3] += a.y * b.w;
            acc[2][0] += a.z * b.x; acc[2][1] += a.z * b.y; acc[2][2] += a.z * b.z; acc[2][3] += a.z * b.w;
            acc[3][0] += a.w * b.x; acc[3][1] += a.w * b.y; acc[3][2] += a.w * b.z; acc[3][3] += a.w * b.w;
        }
        __syncthreads();
    }
    float bcol[4], scol[4], mcol[4], ecol[4];
#pragma unroll
    for (int j = 0; j < 4; ++j) {
        int col = col0 + tn * 4 + j;
        bcol[j] = bias[col];
        scol[j] = gam[col] * rsqrtf(var[col] + EPSc);
        mcol[j] = mu[col];
        ecol[j] = bet[col];
    }
#pragma unroll
    for (int i = 0; i < 4; ++i) {
        int row = row0 + tm * 4 + i;
        if (row >= M) continue;
        bool zero = false;
        if (ZEROEMPTY) zero = (cnt[row] == 0);
        float r[4];
#pragma unroll
        for (int j = 0; j < 4; ++j) {
            float v = acc[i][j] + bcol[j];
            v = (v - mcol[j]) * scol[j] + ecol[j];
            if (RELU) v = fmaxf(v, 0.f);
            if (zero) v = 0.f;
            r[j] = v;
        }
        if (OBF16) {
            ushort4 o;
            o.x = bfbits(r[0]); o.y = bfbits(r[1]); o.z = bfbits(r[2]); o.w = bfbits(r[3]);
            *(ushort4*)((unsigned short*)outv + (size_t)row * 256 + col0 + tn * 4) = o;
        } else {
            float4 o = make_float4(r[0], r[1], r[2], r[3]);
            *(float4*)((float*)outv + (size_t)row * 256 + col0 + tn * 4) = o;
        }
    }
}

// fused: 17-wide aggregation (graph 1) + K=17 GEMM + BN + ReLU, bf16 out
__global__ void agg17_gemm_bn(const float* __restrict__ xb, const int* __restrict__ rp,
                              const unsigned* __restrict__ csw, const float* __restrict__ dinv,
                              const float* __restrict__ W, const float* __restrict__ bias,
                              const float* __restrict__ gam, const float* __restrict__ bet,
                              const float* __restrict__ mu, const float* __restrict__ var,
                              unsigned short* __restrict__ out) {
    int r = blockIdx.x, t = threadIdx.x;   // 256 threads
    __shared__ float zr[17];
    if (t < 17) {
        float di = dinv[r];
        float acc = di * di * xb[(size_t)r * 17 + t];
        int e0 = rp[r], e1 = rp[r + 1];
        for (int e = e0; e < e1; ++e) {
            unsigned ew = csw[e];
            acc += __uint_as_float(ew & 0xffff0000u) * xb[(size_t)(ew & 0xffffu) * 17 + t];
        }
        zr[t] = acc;
    }
    __syncthreads();
    float acc = bias[t];
#pragma unroll
    for (int k = 0; k < 17; ++k) acc += zr[k] * W[k * 256 + t];
    float s = gam[t] * rsqrtf(var[t] + EPSc);
    acc = (acc - mu[t]) * s + bet[t];
    acc = fmaxf(acc, 0.f);
    out[(size_t)r * 256 + t] = bfbits(acc);
}

// ---------------- pooling ----------------

__global__ void pool_mean(const float* __restrict__ z, const int* __restrict__ start,
                          const int* __restrict__ batch, float* __restrict__ p,
                          int* __restrict__ cnt_out, int* __restrict__ bpool) {
    int c = blockIdx.x, t = threadIdx.x;  // 64 threads
    int s = start[c], e = start[c + 1];
    int cnt = e - s;
    const float4* z4 = (const float4*)z;
    float ax = 0.f, ay = 0.f, az = 0.f, aw = 0.f;
    for (int i = s; i < e; ++i) {
        float4 v = z4[(size_t)i * 64 + t];
        ax += v.x; ay += v.y; az += v.z; aw += v.w;
    }
    float inv = 1.0f / (float)max(cnt, 1);
    ((float4*)p)[(size_t)c * 64 + t] = make_float4(ax * inv, ay * inv, az * inv, aw * inv);
    if (t == 0) {
        cnt_out[c] = cnt;
        int sb = 0;
        for (int i = s; i < e; ++i) sb += batch[i];
        bpool[c] = (int)rintf((float)sb * inv);
    }
}

// ---------------- heads ----------------

__global__ void head0(const float* __restrict__ xp, const float* __restrict__ linW,
                      const float* __restrict__ linb, const float* __restrict__ xpool1,
                      float* __restrict__ outp, float* __restrict__ xb) {
    int r = blockIdx.x, t = threadIdx.x;  // 64 threads
    __shared__ float xr[256];
    __shared__ float lg[16];
    __shared__ float ex[16];
#pragma unroll
    for (int j = 0; j < 4; ++j) xr[t + 64 * j] = xp[(size_t)r * 256 + t + 64 * j];
    __syncthreads();
    if (t < 16) {
        float acc = linb[t];
        for (int k = 0; k < 256; ++k) acc += xr[k] * linW[k * 16 + t];
        lg[t] = acc;
    }
    __syncthreads();
    if (t < 16) {
        float mx = lg[0];
#pragma unroll
        for (int c = 1; c < 16; ++c) mx = fmaxf(mx, lg[c]);
        ex[t] = expf(lg[t] - mx);
    }
    __syncthreads();
    if (t < 16) {
        float sum = 0.f;
#pragma unroll
        for (int c = 0; c < 16; ++c) sum += ex[c];
        float pv = ex[t] / sum;
        outp[(size_t)r * 16 + t] = pv;
        xb[(size_t)r * 17 + t] = pv;
    }
    if (t == 16) xb[(size_t)r * 17 + 16] = xpool1[r];
}

// head1 with atomic-free segmented reduction: stage bpool[3000] in LDS, scan
// with a wave-uniform branch (~10 us), accumulate matching zbb rows (coalesced),
// then mean -> layer2 GEMM+BN -> logits -> softmax -> d_out tail.
__global__ void head1(const float* __restrict__ zbb, const int* __restrict__ bpool,
                      const float* __restrict__ W, const float* __restrict__ bias,
                      const float* __restrict__ gam, const float* __restrict__ bet,
                      const float* __restrict__ mu, const float* __restrict__ var,
                      const float* __restrict__ linW, const float* __restrict__ linb,
                      float* __restrict__ outp) {
    int b = blockIdx.x, t = threadIdx.x;  // 16 blocks x 256 threads
    __shared__ int bp[N1c];               // 12 KB
    __shared__ float pr[256];
    __shared__ float yr[256];
    __shared__ float lg[16];
    __shared__ float ex[16];
    for (int i = t; i < N1c; i += 256) bp[i] = bpool[i];
    __syncthreads();
    float acc0 = 0.f;
    int c = 0;
    for (int i = 0; i < N1c; ++i) {
        if (bp[i] == b) {                 // wave-uniform branch
            acc0 += zbb[(size_t)i * 256 + t];
            ++c;
        }
    }
    float inv = 1.0f / (float)max(c, 1);
    pr[t] = acc0 * inv;
    __syncthreads();
    float acc = bias[t];
    for (int k = 0; k < 256; ++k) acc += pr[k] * W[k * 256 + t];
    float s = gam[t] * rsqrtf(var[t] + EPSc);
    acc = (acc - mu[t]) * s + bet[t];
    if (c == 0) acc = 0.f;
    yr[t] = acc;
    __syncthreads();
    if (t < 16) {
        float l = linb[t];
        for (int k = 0; k < 256; ++k) l += yr[k] * linW[k * 16 + t];
        lg[t] = l;
    }
    __syncthreads();
    if (t < 16) {
        float mx = lg[0];
#pragma unroll
        for (int cc = 1; cc < 16; ++cc) mx = fmaxf(mx, lg[cc]);
        ex[t] = expf(lg[t] - mx);
    }
    __syncthreads();
    if (t < 16) {
        float sum = 0.f;
#pragma unroll
        for (int cc = 0; cc < 16; ++cc) sum += ex[cc];
        outp[48000 + b * 16 + t] = ex[t] / sum;
    }
}

// ---------------- launch ----------------

extern "C" void kernel_launch(void* const* d_in, const int* in_sizes, int n_in,
                              void* d_out, int out_size, void* d_ws, size_t ws_size,
                              hipStream_t stream) {
    const float* x       = (const float*)d_in[0];
    const float* x_pool1 = (const float*)d_in[1];
    const float* W_in0   = (const float*)d_in[2];
    const float* W_h0    = (const float*)d_in[3];
    const float* b0      = (const float*)d_in[4];
    const float* g0      = (const float*)d_in[5];
    const float* be0     = (const float*)d_in[6];
    const float* m0      = (const float*)d_in[7];
    const float* v0      = (const float*)d_in[8];
    const float* W_in1   = (const float*)d_in[9];
    const float* W_h1    = (const float*)d_in[10];
    const float* b1      = (const float*)d_in[11];
    const float* g1      = (const float*)d_in[12];
    const float* be1     = (const float*)d_in[13];
    const float* m1      = (const float*)d_in[14];
    const float* v1      = (const float*)d_in[15];
    const float* linW0   = (const float*)d_in[16];
    const float* linb0   = (const float*)d_in[17];
    const float* linW1   = (const float*)d_in[18];
    const float* linb1   = (const float*)d_in[19];
    const int*   ei      = (const int*)d_in[20];
    const int*   batch   = (const int*)d_in[21];
    const int*   pool1   = (const int*)d_in[22];
    const int*   eip     = (const int*)d_in[23];
    float* outp = (float*)d_out;

    // carve workspace (256B-aligned); zero-init block FIRST (single memset)
    char* p = (char*)d_ws;
    auto carve = [&](size_t bytes) -> void* {
        void* r = (void*)p;
        p += (bytes + 255) & ~(size_t)255;
        return r;
    };
    int*   deg    = (int*)  carve((size_t)NALL * 4);   // zeroed
    int*   tmp    = (int*)  carve((size_t)NALL * 4);   // zeroed
    size_t zeroBytes = (size_t)((char*)p - (char*)deg);

    int*   rp     = (int*)  carve((size_t)(NALL + 1) * 4);
    int*   rpf    = (int*)  carve((size_t)(NALL + 1) * 4);
    float* dinv   = (float*)carve((size_t)NALL * 4);
    int*   blkSum = (int*)  carve(256 * 4);
    int*   blkOff = (int*)  carve(256 * 4);
    unsigned* csw = (unsigned*)carve((size_t)EALL * 4);
    // region1: [xbf | z0bf] aliased later by g1bf (15.36 MB total)
    unsigned short* xbf  = (unsigned short*)carve((size_t)N0c * 256 * 2);
    unsigned short* z0bf = xbf + (size_t)N0c * 128;
    unsigned short* g1bf = xbf;                         // alias (xbf,z0bf dead)
    // region2: [g0bf | z1bf] aliased later by bufA (30.72 MB total)
    unsigned short* g0bf = (unsigned short*)carve((size_t)N0c * 256 * 4);
    unsigned short* z1bf = g0bf + (size_t)N0c * 256;
    float* bufA = (float*)g0bf;                         // alias (g0bf,z1bf dead)

    unsigned short* Wt0 = (unsigned short*)carve((size_t)256 * 128 * 2);
    unsigned short* Wt1 = (unsigned short*)carve((size_t)256 * 256 * 2);
    float* sc0 = (float*)carve(256 * 4);
    float* sh0 = (float*)carve(256 * 4);
    float* sc1 = (float*)carve(256 * 4);
    float* sh1 = (float*)carve(256 * 4);

    int*   start0 = (int*)  carve((size_t)(N1c + 1) * 4);
    int*   cnt0   = (int*)  carve((size_t)N1c * 4);
    float* pmean  = (float*)carve((size_t)N1c * 256 * 4);
    float* xp     = (float*)carve((size_t)N1c * 256 * 4);
    float* xb     = (float*)carve((size_t)N1c * 17 * 4);
    int*   bpool  = (int*)  carve((size_t)N1c * 4);
    unsigned short* hbbbf = (unsigned short*)carve((size_t)N1c * 256 * 2);
    float* zbb    = (float*)carve((size_t)N1c * 256 * 4);

    hipMemsetAsync(deg, 0, zeroBytes, stream);

    const int* src0 = ei;
    const int* dst0 = ei + E0c;
    const int* src1 = eip;
    const int* dst1 = eip + E1c;

    // ---- unified CSR build (4 dispatches) ----
    count_deg_all<<<cdiv_i(EALL, 256), 256, 0, stream>>>(dst0, dst1, deg);
    int nb = cdiv_i(NALL, 256);
    scan_block<<<nb, 256, 0, stream>>>(deg, NALL, rp, blkSum, dinv);
    scan_sums<<<1, 256, 0, stream>>>(blkSum, nb, blkOff, rp, NALL);
    megaprep<<<NB_FILL + NB_RPF + NB_CVT + NB_PW + NB_SEG, 256, 0, stream>>>(
        src0, dst0, src1, dst1, rp, blkOff, tmp, dinv, csw, rpf, x, xbf,
        W_in0, W_h0, b0, g0, be0, m0, v0, Wt0, Wt1, sc0, sh0, sc1, sh1,
        pool1, start0);

    const int*   rp1   = rpf + N0c;
    const float* dinv1 = dinv + N0c;

    // ---- phase A: 3 GCN layers on N0 (layers 0/1: bf16 MFMA path) ----
    agg_bf16<16, 2, true><<<2 * cdiv_i(N0c, 4), 256, 0, stream>>>(xbf, rpf, csw, dinv, z0bf, N0c);
    gemm_mfma_bn<128><<<cdiv_i(N0c, 64), 256, 0, stream>>>(z0bf, Wt0, sc0, sh0, g0bf, N0c);
    agg_bf16<32, 4, true><<<4 * cdiv_i(N0c, 4), 256, 0, stream>>>(g0bf, rpf, csw, dinv, z1bf, N0c);
    gemm_mfma_bn<256><<<cdiv_i(N0c, 64), 256, 0, stream>>>(z1bf, Wt1, sc1, sh1, g1bf, N0c);
    agg_bf16<32, 4, false><<<4 * cdiv_i(N0c, 4), 256, 0, stream>>>(g1bf, rpf, csw, dinv, bufA, N0c);

    // layer 2: pool BEFORE GEMM (affine reorder); fp32 vector GEMM (precision)
    pool_mean<<<N1c, 64, 0, stream>>>(bufA, start0, batch, pmean, cnt0, bpool);
    gemm_bn<256, false, true, false><<<dim3(cdiv_i(N1c, 64), 4), 256, 0, stream>>>(
        pmean, W_h0 + Hc * Hc, b0 + 2 * Hc, g0 + 2 * Hc, be0 + 2 * Hc, m0 + 2 * Hc,
        v0 + 2 * Hc, cnt0, xp, N1c);

    // head0: logits + softmax -> d_out[0:48000], xb = [x0 | x_pool1]
    head0<<<N1c, 64, 0, stream>>>(xp, linW0, linb0, x_pool1, outp, xb);

    // ---- phase B: 3 GCN layers on N1 (fp32 vector GEMMs) ----
    agg17_gemm_bn<<<N1c, 256, 0, stream>>>(xb, rp1, csw, dinv1, W_in1, b1, g1, be1,
                                           m1, v1, hbbbf);
    agg_bf16<32, 4, false><<<4 * cdiv_i(N1c, 4), 256, 0, stream>>>(hbbbf, rp1, csw, dinv1, zbb, N1c);
    gemm_bn<256, true, false, true><<<dim3(cdiv_i(N1c, 64), 4), 256, 0, stream>>>(
        zbb, W_h1, b1 + Hc, g1 + Hc, be1 + Hc, m1 + Hc, v1 + Hc, nullptr, hbbbf, N1c);
    agg_bf16<32, 4, false><<<4 * cdiv_i(N1c, 4), 256, 0, stream>>>(hbbbf, rp1, csw, dinv1, zbb, N1c);

    // head1: atomic-free 3000->16 segmented reduction + layer2 GEMM+BN + logits
    // + softmax -> d_out[48000:48256]
    head1<<<Bc, 256, 0, stream>>>(zbb, bpool, W_h1 + Hc * Hc, b1 + 2 * Hc, g1 + 2 * Hc,
                                  be1 + 2 * Hc, m1 + 2 * Hc, v1 + 2 * Hc, linW1, linb1,
                                  outp);
}

// Round 12
// 486.025 us; speedup vs baseline: 1.3640x; 1.3640x over previous
//
#include <hip/hip_runtime.h>
#include <cstdint>
#include <cstddef>

// Problem constants
#define N0c 30000
#define F0c 128
#define Hc  256
#define Cc  16
#define N1c 3000
#define Bc  16
#define E0c 960000
#define E1c 48000
#define NALL 33000            // N0 + N1 (concatenated graphs)
#define EALL 1008000          // E0 + E1
#define EPSc 1e-5f
#define SLICE 188             // clusters per pool_b_partial slice (16*188 >= 3000)

static __host__ __device__ inline int cdiv_i(int a, int b) { return (a + b - 1) / b; }

// round-to-nearest-even fp32 -> bf16 (returns the 16 bf16 bits)
static __device__ inline unsigned short bfbits(float f) {
    unsigned u = __float_as_uint(f);
    return (unsigned short)((u + 0x7fffu + ((u >> 16) & 1u)) >> 16);
}

typedef short short8 __attribute__((ext_vector_type(8)));   // 8 bf16 = 4 VGPRs
typedef float floatx4 __attribute__((ext_vector_type(4)));

// ---------------- graph preprocessing (both graphs concatenated) ----------------

__global__ void count_deg_all(const int* __restrict__ dst0, const int* __restrict__ dst1,
                              int* __restrict__ deg) {
    int e = blockIdx.x * blockDim.x + threadIdx.x;
    if (e < E0c) atomicAdd(&deg[dst0[e]], 1);
    else if (e < EALL) atomicAdd(&deg[N0c + dst1[e - E0c]], 1);
}

// scan + dinv fused: dinv[i] = rsqrt(deg[i]+1)
__global__ void scan_block(const int* __restrict__ cnt, int n, int* __restrict__ rp,
                           int* __restrict__ blkSum, float* __restrict__ dinv) {
    __shared__ int sh[256];
    int t = threadIdx.x;
    int i = blockIdx.x * 256 + t;
    int v = (i < n) ? cnt[i] : 0;
    if (i < n) dinv[i] = rsqrtf((float)(v + 1));
    sh[t] = v; __syncthreads();
    for (int off = 1; off < 256; off <<= 1) {
        int add = (t >= off) ? sh[t - off] : 0;
        __syncthreads();
        sh[t] += add;
        __syncthreads();
    }
    if (i < n) rp[i] = sh[t] - v;
    if (t == 255) blkSum[blockIdx.x] = sh[255];
}

__global__ void scan_sums(const int* __restrict__ blkSum, int nb, int* __restrict__ blkOff,
                          int* __restrict__ rp, int n) {
    __shared__ int sh[256];
    int t = threadIdx.x;
    int v = (t < nb) ? blkSum[t] : 0;
    sh[t] = v; __syncthreads();
    for (int off = 1; off < 256; off <<= 1) {
        int add = (t >= off) ? sh[t - off] : 0;
        __syncthreads();
        sh[t] += add;
        __syncthreads();
    }
    blkOff[t] = sh[t] - v;
    if (t == 255) rp[n] = sh[255];
}

// ---------------- mega-prep: all post-scan independent work in ONE kernel ------
#define NB_FILL 3938
#define NB_RPF  129
#define NB_CVT  3750
#define NB_PW   386
#define NB_SEG  118

__global__ void megaprep(const int* __restrict__ src0, const int* __restrict__ dst0,
                         const int* __restrict__ src1, const int* __restrict__ dst1,
                         const int* __restrict__ rp, const int* __restrict__ blkOff,
                         int* __restrict__ tmp, const float* __restrict__ dinv,
                         unsigned* __restrict__ csw, int* __restrict__ rpf,
                         const float* __restrict__ x, unsigned short* __restrict__ xbf,
                         const float* __restrict__ W_in0, const float* __restrict__ W_h0,
                         const float* __restrict__ b0, const float* __restrict__ g0,
                         const float* __restrict__ be0, const float* __restrict__ m0,
                         const float* __restrict__ v0,
                         unsigned short* __restrict__ Wt0, unsigned short* __restrict__ Wt1,
                         float* __restrict__ sc0, float* __restrict__ sh0,
                         float* __restrict__ sc1, float* __restrict__ sh1,
                         const int* __restrict__ pool1, int* __restrict__ start0) {
    int bx = blockIdx.x, t = threadIdx.x;
    if (bx < NB_FILL) {
        int e = bx * 256 + t;
        if (e >= EALL) return;
        int s, d;
        if (e < E0c) { s = src0[e]; d = dst0[e]; }
        else         { s = N0c + src1[e - E0c]; d = N0c + dst1[e - E0c]; }
        int pos = rp[d] + blkOff[d >> 8] + atomicAdd(&tmp[d], 1);
        float w = dinv[s] * dinv[d];
        int sloc = (e < E0c) ? s : (s - N0c);
        csw[pos] = ((unsigned)bfbits(w) << 16) | (unsigned)sloc;
    } else if (bx < NB_FILL + NB_RPF) {
        int i = (bx - NB_FILL) * 256 + t;
        if (i < NALL) rpf[i] = rp[i] + blkOff[i >> 8];
        else if (i == NALL) rpf[NALL] = rp[NALL];   // total (already final)
    } else if (bx < NB_FILL + NB_RPF + NB_CVT) {
        int i = (bx - NB_FILL - NB_RPF) * 256 + t;  // float4 index
        if (i >= N0c * 32) return;
        float4 v = ((const float4*)x)[i];
        ushort4 o;
        o.x = bfbits(v.x); o.y = bfbits(v.y); o.z = bfbits(v.z); o.w = bfbits(v.w);
        ((ushort4*)xbf)[i] = o;
    } else if (bx < NB_FILL + NB_RPF + NB_CVT + NB_PW) {
        int pb = bx - NB_FILL - NB_RPF - NB_CVT;
        if (pb < 128) {
            int i = pb * 256 + t;
            int k = i >> 8, col = i & 255;
            Wt0[col * 128 + k] = bfbits(W_in0[i]);
        } else if (pb < 384) {
            int i = (pb - 128) * 256 + t;
            int k = i >> 8, col = i & 255;
            Wt1[col * 256 + k] = bfbits(W_h0[i]);
        } else if (pb == 384) {
            float s = g0[t] * rsqrtf(v0[t] + EPSc);
            sc0[t] = s;
            sh0[t] = (b0[t] - m0[t]) * s + be0[t];
        } else {
            int tt = t + 256;
            float s = g0[tt] * rsqrtf(v0[tt] + EPSc);
            sc1[t] = s;
            sh1[t] = (b0[tt] - m0[tt]) * s + be0[tt];
        }
    } else {
        int i = (bx - NB_FILL - NB_RPF - NB_CVT - NB_PW) * 256 + t;
        if (i > N0c) return;
        if (i == 0) {
            for (int c = 0; c <= pool1[0]; ++c) start0[c] = 0;
        } else if (i == N0c) {
            for (int c = pool1[N0c - 1] + 1; c <= N1c; ++c) start0[c] = N0c;
        } else {
            int a = pool1[i - 1], b = pool1[i];
            for (int c = a + 1; c <= b; ++c) start0[c] = i;
        }
    }
}

// ---------------- aggregation (bf16 gather, fp32 accumulate) ----------------

static __device__ inline void acc8(float a[8], float w, uint4 v) {
    a[0] += w * __uint_as_float(v.x << 16);
    a[1] += w * __uint_as_float(v.x & 0xffff0000u);
    a[2] += w * __uint_as_float(v.y << 16);
    a[3] += w * __uint_as_float(v.y & 0xffff0000u);
    a[4] += w * __uint_as_float(v.z << 16);
    a[5] += w * __uint_as_float(v.z & 0xffff0000u);
    a[6] += w * __uint_as_float(v.w << 16);
    a[7] += w * __uint_as_float(v.w & 0xffff0000u);
}

// RSU: bf16 row stride in 16B units (16 for 128-wide, 32 for 256-wide).
// NCHUNK chunks of 64 cols; chunk = blockIdx&(NCHUNK-1) pins chunks to XCD sets.
// 32-bit gather addressing; wave-uniform trip count + unroll-by-2 ILP.
// OBF16: write bf16 rows (feeds MFMA) else fp32 rows. NO atomics anywhere.
template <int RSU, int NCHUNK, bool OBF16>
__global__ __launch_bounds__(256) void agg_bf16(
    const unsigned short* __restrict__ x, const int* __restrict__ rp,
    const unsigned* __restrict__ csw, const float* __restrict__ dinv,
    void* __restrict__ zv, int N) {
    constexpr int SHIFT = (RSU == 32) ? 9 : 8;   // log2(row bytes)
    int b = blockIdx.x;
    int chunk = b & (NCHUNK - 1);
    int node = (b / NCHUNK) * 4 + (threadIdx.x >> 6);
    if (node >= N) return;
    int lane = threadIdx.x & 63;
    int par = lane >> 3;
    int cl = lane & 7;
    int c4 = chunk * 8 + cl;             // uint4 index within bf16 row
    const char* xb = (const char*)x;
    unsigned coff = (unsigned)c4 << 4;   // byte offset of this lane's 16B slice
    float a[8] = {0.f, 0.f, 0.f, 0.f, 0.f, 0.f, 0.f, 0.f};
    if (par == 0) {                      // self-loop term exactly once
        float di = dinv[node];
        uint4 v = *(const uint4*)(xb + (((unsigned)node << SHIFT) + coff));
        acc8(a, di * di, v);
    }
    int e0 = rp[node], e1 = rp[node + 1];
    for (int base = e0; base < e1; base += 64) {
        int batch = e1 - base;
        if (batch > 64) batch = 64;
        unsigned my = 0;
        if (lane < batch) my = csw[base + lane];   // up to 64 edges in ONE load
        int full = batch >> 3;                      // wave-uniform trip count
        int i = 0;
        for (; i + 1 < full; i += 2) {              // 2 gathers in flight
            unsigned ew0 = (unsigned)__shfl((int)my, i * 8 + par, 64);
            unsigned ew1 = (unsigned)__shfl((int)my, i * 8 + 8 + par, 64);
            uint4 v0 = *(const uint4*)(xb + (((ew0 & 0xffffu) << SHIFT) + coff));
            uint4 v1 = *(const uint4*)(xb + (((ew1 & 0xffffu) << SHIFT) + coff));
            acc8(a, __uint_as_float(ew0 & 0xffff0000u), v0);
            acc8(a, __uint_as_float(ew1 & 0xffff0000u), v1);
        }
        if (i < full) {
            unsigned ew = (unsigned)__shfl((int)my, i * 8 + par, 64);
            uint4 v = *(const uint4*)(xb + (((ew & 0xffffu) << SHIFT) + coff));
            acc8(a, __uint_as_float(ew & 0xffff0000u), v);
        }
        int rem = batch & 7;
        if (rem) {                                  // single guarded tail step
            unsigned ew = (unsigned)__shfl((int)my, full * 8 + par, 64);
            if (par < rem) {
                unsigned off = ((ew & 0xffffu) << SHIFT) + coff;
                float w = __uint_as_float(ew & 0xffff0000u);
                uint4 v = *(const uint4*)(xb + off);
                acc8(a, w, v);
            }
        }
    }
#pragma unroll
    for (int m = 8; m < 64; m <<= 1) {
#pragma unroll
        for (int k = 0; k < 8; ++k) a[k] += __shfl_xor(a[k], m, 64);
    }
    if (par == 0) {
        if (OBF16) {
            uint4 o;
            o.x = (unsigned)bfbits(a[0]) | ((unsigned)bfbits(a[1]) << 16);
            o.y = (unsigned)bfbits(a[2]) | ((unsigned)bfbits(a[3]) << 16);
            o.z = (unsigned)bfbits(a[4]) | ((unsigned)bfbits(a[5]) << 16);
            o.w = (unsigned)bfbits(a[6]) | ((unsigned)bfbits(a[7]) << 16);
            ((uint4*)zv)[(size_t)node * RSU + c4] = o;
        } else {
            float4* zp = (float4*)zv + (size_t)node * (RSU * 2) + c4 * 2;
            zp[0] = make_float4(a[0], a[1], a[2], a[3]);
            zp[1] = make_float4(a[4], a[5], a[6], a[7]);
        }
    }
}

// ---------------- MFMA bf16 GEMM: (M x K)bf16 @ Wt(256 x K)bf16 -> bf16 out ----

template <int K>
__global__ __launch_bounds__(256) void gemm_mfma_bn(
    const unsigned short* __restrict__ A, const unsigned short* __restrict__ Wt,
    const float* __restrict__ sc, const float* __restrict__ sh,
    unsigned short* __restrict__ out, int M) {
    constexpr int LDS_S = 40;
    __shared__ unsigned short As[64 * LDS_S];
    __shared__ unsigned short Bs[256 * LDS_S];
    int tid = threadIdx.x;
    int w = tid >> 6, l = tid & 63;
    int quad = l >> 4, lm = l & 15;
    int row0 = blockIdx.x * 64;
    floatx4 acc[4][4];
#pragma unroll
    for (int i = 0; i < 4; ++i)
#pragma unroll
        for (int j = 0; j < 4; ++j) acc[i][j] = (floatx4){0.f, 0.f, 0.f, 0.f};

    int ar = tid >> 2;          // A staging: row 0..63
    int ac = (tid & 3) * 8;     // short offset 0,8,16,24

    for (int k0 = 0; k0 < K; k0 += 32) {
        uint4 av = make_uint4(0, 0, 0, 0);
        if (row0 + ar < M) av = *(const uint4*)(A + (size_t)(row0 + ar) * K + k0 + ac);
        *(uint4*)&As[ar * LDS_S + ac] = av;
#pragma unroll
        for (int c = 0; c < 4; ++c) {    // Bs: thread -> col tid, 4 k-chunks
            uint4 bv = *(const uint4*)(Wt + (size_t)tid * K + k0 + c * 8);
            *(uint4*)&Bs[tid * LDS_S + c * 8] = bv;
        }
        __syncthreads();
        short8 af[4], bf[4];
#pragma unroll
        for (int i = 0; i < 4; ++i)
            af[i] = *(const short8*)&As[(i * 16 + lm) * LDS_S + quad * 8];
#pragma unroll
        for (int j = 0; j < 4; ++j)
            bf[j] = *(const short8*)&Bs[(w * 64 + j * 16 + lm) * LDS_S + quad * 8];
#pragma unroll
        for (int i = 0; i < 4; ++i)
#pragma unroll
            for (int j = 0; j < 4; ++j)
                acc[i][j] = __builtin_amdgcn_mfma_f32_16x16x32_bf16(af[i], bf[j], acc[i][j], 0, 0, 0);
        __syncthreads();
    }
    // epilogue: C/D map col=lane&15, row=quad*4+reg [verified m89/m91]
#pragma unroll
    for (int j = 0; j < 4; ++j) {
        int col = w * 64 + j * 16 + lm;
        float s = sc[col], h = sh[col];
#pragma unroll
        for (int i = 0; i < 4; ++i) {
            int rb = row0 + i * 16 + quad * 4;
#pragma unroll
            for (int r = 0; r < 4; ++r) {
                int row = rb + r;
                if (row < M) {
                    float v = acc[i][j][r] * s + h;
                    v = fmaxf(v, 0.f);
                    out[(size_t)row * 256 + col] = bfbits(v);
                }
            }
        }
    }
}

// ---------------- fp32 vector GEMM (kept for small M=3000, precision-critical) --

template <int K, bool RELU, bool ZEROEMPTY, bool OBF16>
__global__ __launch_bounds__(256) void gemm_bn(
    const float* __restrict__ A, const float* __restrict__ W,
    const float* __restrict__ bias, const float* __restrict__ gam,
    const float* __restrict__ bet, const float* __restrict__ mu,
    const float* __restrict__ var, const int* __restrict__ cnt,
    void* __restrict__ outv, int M) {
    __shared__ __align__(16) float As[16][64];
    __shared__ __align__(16) float Bs[16][64];
    int tid = threadIdx.x;
    int tm = tid >> 4, tn = tid & 15;
    int row0 = blockIdx.x * 64, col0 = blockIdx.y * 64;
    float acc[4][4] = {};
    int ar = tid >> 2;
    int ak = (tid & 3) * 4;
    int bk = tid >> 4;
    int bn = (tid & 15) * 4;

    for (int kk = 0; kk < K; kk += 16) {
        float4 av = make_float4(0.f, 0.f, 0.f, 0.f);
        int grow = row0 + ar;
        if (grow < M) av = *(const float4*)(A + (size_t)grow * K + kk + ak);
        As[ak + 0][ar] = av.x;
        As[ak + 1][ar] = av.y;
        As[ak + 2][ar] = av.z;
        As[ak + 3][ar] = av.w;
        float4 bv = *(const float4*)(W + (size_t)(kk + bk) * 256 + col0 + bn);
        *(float4*)&Bs[bk][bn] = bv;
        __syncthreads();
#pragma unroll
        for (int k = 0; k < 16; ++k) {
            float4 a = *(const float4*)&As[k][tm * 4];
            float4 b = *(const float4*)&Bs[k][tn * 4];
            acc[0][0] += a.x * b.x; acc[0][1] += a.x * b.y; acc[0][2] += a.x * b.z; acc[0][3] += a.x * b.w;
            acc[1][0] += a.y * b.x; acc[1][1] += a.y * b.y; acc[1][2] += a.y * b.z; acc[1][3] += a.y * b.w;
            acc[2][0] += a.z * b.x; acc[2][1] += a.z * b.y; acc[2][2] += a.z * b.z; acc[2][3] += a.z * b.w;
            acc[3][0] += a.w * b.x; acc[3][1] += a.w * b.y; acc[3][2] += a.w * b.z; acc[3][3] += a.w * b.w;
        }
        __syncthreads();
    }
    float bcol[4], scol[4], mcol[4], ecol[4];
#pragma unroll
    for (int j = 0; j < 4; ++j) {
        int col = col0 + tn * 4 + j;
        bcol[j] = bias[col];
        scol[j] = gam[col] * rsqrtf(var[col] + EPSc);
        mcol[j] = mu[col];
        ecol[j] = bet[col];
    }
#pragma unroll
    for (int i = 0; i < 4; ++i) {
        int row = row0 + tm * 4 + i;
        if (row >= M) continue;
        bool zero = false;
        if (ZEROEMPTY) zero = (cnt[row] == 0);
        float r[4];
#pragma unroll
        for (int j = 0; j < 4; ++j) {
            float v = acc[i][j] + bcol[j];
            v = (v - mcol[j]) * scol[j] + ecol[j];
            if (RELU) v = fmaxf(v, 0.f);
            if (zero) v = 0.f;
            r[j] = v;
        }
        if (OBF16) {
            ushort4 o;
            o.x = bfbits(r[0]); o.y = bfbits(r[1]); o.z = bfbits(r[2]); o.w = bfbits(r[3]);
            *(ushort4*)((unsigned short*)outv + (size_t)row * 256 + col0 + tn * 4) = o;
        } else {
            float4 o = make_float4(r[0], r[1], r[2], r[3]);
            *(float4*)((float*)outv + (size_t)row * 256 + col0 + tn * 4) = o;
        }
    }
}

// fused: 17-wide aggregation (graph 1) + K=17 GEMM + BN + ReLU, bf16 out
__global__ void agg17_gemm_bn(const float* __restrict__ xb, const int* __restrict__ rp,
                              const unsigned* __restrict__ csw, const float* __restrict__ dinv,
                              const float* __restrict__ W, const float* __restrict__ bias,
                              const float* __restrict__ gam, const float* __restrict__ bet,
                              const float* __restrict__ mu, const float* __restrict__ var,
                              unsigned short* __restrict__ out) {
    int r = blockIdx.x, t = threadIdx.x;   // 256 threads
    __shared__ float zr[17];
    if (t < 17) {
        float di = dinv[r];
        float acc = di * di * xb[(size_t)r * 17 + t];
        int e0 = rp[r], e1 = rp[r + 1];
        for (int e = e0; e < e1; ++e) {
            unsigned ew = csw[e];
            acc += __uint_as_float(ew & 0xffff0000u) * xb[(size_t)(ew & 0xffffu) * 17 + t];
        }
        zr[t] = acc;
    }
    __syncthreads();
    float acc = bias[t];
#pragma unroll
    for (int k = 0; k < 17; ++k) acc += zr[k] * W[k * 256 + t];
    float s = gam[t] * rsqrtf(var[t] + EPSc);
    acc = (acc - mu[t]) * s + bet[t];
    acc = fmaxf(acc, 0.f);
    out[(size_t)r * 256 + t] = bfbits(acc);
}

// ---------------- pooling ----------------

__global__ void pool_mean(const float* __restrict__ z, const int* __restrict__ start,
                          const int* __restrict__ batch, float* __restrict__ p,
                          int* __restrict__ cnt_out, int* __restrict__ bpool) {
    int c = blockIdx.x, t = threadIdx.x;  // 64 threads
    int s = start[c], e = start[c + 1];
    int cnt = e - s;
    const float4* z4 = (const float4*)z;
    float ax = 0.f, ay = 0.f, az = 0.f, aw = 0.f;
    for (int i = s; i < e; ++i) {
        float4 v = z4[(size_t)i * 64 + t];
        ax += v.x; ay += v.y; az += v.z; aw += v.w;
    }
    float inv = 1.0f / (float)max(cnt, 1);
    ((float4*)p)[(size_t)c * 64 + t] = make_float4(ax * inv, ay * inv, az * inv, aw * inv);
    if (t == 0) {
        cnt_out[c] = cnt;
        int sb = 0;
        for (int i = s; i < e; ++i) sb += batch[i];
        bpool[c] = (int)rintf((float)sb * inv);
    }
}

// stage 1 of atomic-free 3000->16 reduction: 256 blocks = 16 graphs x 16 slices.
// Unconditional row loads (predicate multiply) keep loads pipelined — no branch
// gating, no atomics, deterministic order.
__global__ __launch_bounds__(256) void pool_b_partial(
    const float* __restrict__ zbb, const int* __restrict__ bpool,
    float* __restrict__ part, int* __restrict__ pcnt) {
    int b = blockIdx.x;          // 0..255
    int g = b & 15, s = b >> 4;
    int t = threadIdx.x;
    int i0 = s * SLICE;
    int n = min(N1c - i0, SLICE);
    __shared__ int bp[SLICE];
    for (int i = t; i < n; i += 256) bp[i] = bpool[i0 + i];
    __syncthreads();
    float acc = 0.f;
    int c = 0;
    for (int i = 0; i < n; ++i) {
        int hit = (bp[i] == g);
        float sel = hit ? 1.f : 0.f;
        acc += sel * zbb[(size_t)(i0 + i) * 256 + t];   // load NOT branch-gated
        c += hit;
    }
    part[(size_t)b * 256 + t] = acc;
    if (t == 0) pcnt[b] = c;
}

// ---------------- heads ----------------

__global__ void head0(const float* __restrict__ xp, const float* __restrict__ linW,
                      const float* __restrict__ linb, const float* __restrict__ xpool1,
                      float* __restrict__ outp, float* __restrict__ xb) {
    int r = blockIdx.x, t = threadIdx.x;  // 64 threads
    __shared__ float xr[256];
    __shared__ float lg[16];
    __shared__ float ex[16];
#pragma unroll
    for (int j = 0; j < 4; ++j) xr[t + 64 * j] = xp[(size_t)r * 256 + t + 64 * j];
    __syncthreads();
    if (t < 16) {
        float acc = linb[t];
        for (int k = 0; k < 256; ++k) acc += xr[k] * linW[k * 16 + t];
        lg[t] = acc;
    }
    __syncthreads();
    if (t < 16) {
        float mx = lg[0];
#pragma unroll
        for (int c = 1; c < 16; ++c) mx = fmaxf(mx, lg[c]);
        ex[t] = expf(lg[t] - mx);
    }
    __syncthreads();
    if (t < 16) {
        float sum = 0.f;
#pragma unroll
        for (int c = 0; c < 16; ++c) sum += ex[c];
        float pv = ex[t] / sum;
        outp[(size_t)r * 16 + t] = pv;
        xb[(size_t)r * 17 + t] = pv;
    }
    if (t == 16) xb[(size_t)r * 17 + 16] = xpool1[r];
}

// head1: sum 16 partials -> mean -> layer2 GEMM+BN -> logits -> softmax
__global__ void head1(const float* __restrict__ part, const int* __restrict__ pcnt,
                      const float* __restrict__ W, const float* __restrict__ bias,
                      const float* __restrict__ gam, const float* __restrict__ bet,
                      const float* __restrict__ mu, const float* __restrict__ var,
                      const float* __restrict__ linW, const float* __restrict__ linb,
                      float* __restrict__ outp) {
    int b = blockIdx.x, t = threadIdx.x;  // 16 blocks x 256 threads
    __shared__ float pr[256];
    __shared__ float yr[256];
    __shared__ float lg[16];
    __shared__ float ex[16];
    float acc0 = 0.f;
    int c = 0;
#pragma unroll
    for (int s = 0; s < 16; ++s) {
        int pb = s * 16 + b;
        acc0 += part[(size_t)pb * 256 + t];
        c += pcnt[pb];
    }
    float inv = 1.0f / (float)max(c, 1);
    pr[t] = acc0 * inv;
    __syncthreads();
    float acc = bias[t];
    for (int k = 0; k < 256; ++k) acc += pr[k] * W[k * 256 + t];
    float s = gam[t] * rsqrtf(var[t] + EPSc);
    acc = (acc - mu[t]) * s + bet[t];
    if (c == 0) acc = 0.f;
    yr[t] = acc;
    __syncthreads();
    if (t < 16) {
        float l = linb[t];
        for (int k = 0; k < 256; ++k) l += yr[k] * linW[k * 16 + t];
        lg[t] = l;
    }
    __syncthreads();
    if (t < 16) {
        float mx = lg[0];
#pragma unroll
        for (int cc = 1; cc < 16; ++cc) mx = fmaxf(mx, lg[cc]);
        ex[t] = expf(lg[t] - mx);
    }
    __syncthreads();
    if (t < 16) {
        float sum = 0.f;
#pragma unroll
        for (int cc = 0; cc < 16; ++cc) sum += ex[cc];
        outp[48000 + b * 16 + t] = ex[t] / sum;
    }
}

// ---------------- launch ----------------

extern "C" void kernel_launch(void* const* d_in, const int* in_sizes, int n_in,
                              void* d_out, int out_size, void* d_ws, size_t ws_size,
                              hipStream_t stream) {
    const float* x       = (const float*)d_in[0];
    const float* x_pool1 = (const float*)d_in[1];
    const float* W_in0   = (const float*)d_in[2];
    const float* W_h0    = (const float*)d_in[3];
    const float* b0      = (const float*)d_in[4];
    const float* g0      = (const float*)d_in[5];
    const float* be0     = (const float*)d_in[6];
    const float* m0      = (const float*)d_in[7];
    const float* v0      = (const float*)d_in[8];
    const float* W_in1   = (const float*)d_in[9];
    const float* W_h1    = (const float*)d_in[10];
    const float* b1      = (const float*)d_in[11];
    const float* g1      = (const float*)d_in[12];
    const float* be1     = (const float*)d_in[13];
    const float* m1      = (const float*)d_in[14];
    const float* v1      = (const float*)d_in[15];
    const float* linW0   = (const float*)d_in[16];
    const float* linb0   = (const float*)d_in[17];
    const float* linW1   = (const float*)d_in[18];
    const float* linb1   = (const float*)d_in[19];
    const int*   ei      = (const int*)d_in[20];
    const int*   batch   = (const int*)d_in[21];
    const int*   pool1   = (const int*)d_in[22];
    const int*   eip     = (const int*)d_in[23];
    float* outp = (float*)d_out;

    // carve workspace (256B-aligned); zero-init block FIRST (single memset)
    char* p = (char*)d_ws;
    auto carve = [&](size_t bytes) -> void* {
        void* r = (void*)p;
        p += (bytes + 255) & ~(size_t)255;
        return r;
    };
    int*   deg    = (int*)  carve((size_t)NALL * 4);   // zeroed
    int*   tmp    = (int*)  carve((size_t)NALL * 4);   // zeroed
    size_t zeroBytes = (size_t)((char*)p - (char*)deg);

    int*   rp     = (int*)  carve((size_t)(NALL + 1) * 4);
    int*   rpf    = (int*)  carve((size_t)(NALL + 1) * 4);
    float* dinv   = (float*)carve((size_t)NALL * 4);
    int*   blkSum = (int*)  carve(256 * 4);
    int*   blkOff = (int*)  carve(256 * 4);
    unsigned* csw = (unsigned*)carve((size_t)EALL * 4);
    // region1: [xbf | z0bf] aliased later by g1bf (15.36 MB total)
    unsigned short* xbf  = (unsigned short*)carve((size_t)N0c * 256 * 2);
    unsigned short* z0bf = xbf + (size_t)N0c * 128;
    unsigned short* g1bf = xbf;                         // alias (xbf,z0bf dead)
    // region2: [g0bf | z1bf] aliased later by bufA (30.72 MB total)
    unsigned short* g0bf = (unsigned short*)carve((size_t)N0c * 256 * 4);
    unsigned short* z1bf = g0bf + (size_t)N0c * 256;
    float* bufA = (float*)g0bf;                         // alias (g0bf,z1bf dead)

    unsigned short* Wt0 = (unsigned short*)carve((size_t)256 * 128 * 2);
    unsigned short* Wt1 = (unsigned short*)carve((size_t)256 * 256 * 2);
    float* sc0 = (float*)carve(256 * 4);
    float* sh0 = (float*)carve(256 * 4);
    float* sc1 = (float*)carve(256 * 4);
    float* sh1 = (float*)carve(256 * 4);

    int*   start0 = (int*)  carve((size_t)(N1c + 1) * 4);
    int*   cnt0   = (int*)  carve((size_t)N1c * 4);
    float* pmean  = (float*)carve((size_t)N1c * 256 * 4);
    float* xp     = (float*)carve((size_t)N1c * 256 * 4);
    float* xb     = (float*)carve((size_t)N1c * 17 * 4);
    int*   bpool  = (int*)  carve((size_t)N1c * 4);
    unsigned short* hbbbf = (unsigned short*)carve((size_t)N1c * 256 * 2);
    float* zbb    = (float*)carve((size_t)N1c * 256 * 4);
    float* part   = (float*)carve((size_t)256 * 256 * 4);
    int*   pcnt   = (int*)  carve((size_t)256 * 4);

    hipMemsetAsync(deg, 0, zeroBytes, stream);

    const int* src0 = ei;
    const int* dst0 = ei + E0c;
    const int* src1 = eip;
    const int* dst1 = eip + E1c;

    // ---- unified CSR build (4 dispatches) ----
    count_deg_all<<<cdiv_i(EALL, 256), 256, 0, stream>>>(dst0, dst1, deg);
    int nb = cdiv_i(NALL, 256);
    scan_block<<<nb, 256, 0, stream>>>(deg, NALL, rp, blkSum, dinv);
    scan_sums<<<1, 256, 0, stream>>>(blkSum, nb, blkOff, rp, NALL);
    megaprep<<<NB_FILL + NB_RPF + NB_CVT + NB_PW + NB_SEG, 256, 0, stream>>>(
        src0, dst0, src1, dst1, rp, blkOff, tmp, dinv, csw, rpf, x, xbf,
        W_in0, W_h0, b0, g0, be0, m0, v0, Wt0, Wt1, sc0, sh0, sc1, sh1,
        pool1, start0);

    const int*   rp1   = rpf + N0c;
    const float* dinv1 = dinv + N0c;

    // ---- phase A: 3 GCN layers on N0 (layers 0/1: bf16 MFMA path) ----
    agg_bf16<16, 2, true><<<2 * cdiv_i(N0c, 4), 256, 0, stream>>>(xbf, rpf, csw, dinv, z0bf, N0c);
    gemm_mfma_bn<128><<<cdiv_i(N0c, 64), 256, 0, stream>>>(z0bf, Wt0, sc0, sh0, g0bf, N0c);
    agg_bf16<32, 4, true><<<4 * cdiv_i(N0c, 4), 256, 0, stream>>>(g0bf, rpf, csw, dinv, z1bf, N0c);
    gemm_mfma_bn<256><<<cdiv_i(N0c, 64), 256, 0, stream>>>(z1bf, Wt1, sc1, sh1, g1bf, N0c);
    agg_bf16<32, 4, false><<<4 * cdiv_i(N0c, 4), 256, 0, stream>>>(g1bf, rpf, csw, dinv, bufA, N0c);

    // layer 2: pool BEFORE GEMM (affine reorder); fp32 vector GEMM (precision)
    pool_mean<<<N1c, 64, 0, stream>>>(bufA, start0, batch, pmean, cnt0, bpool);
    gemm_bn<256, false, true, false><<<dim3(cdiv_i(N1c, 64), 4), 256, 0, stream>>>(
        pmean, W_h0 + Hc * Hc, b0 + 2 * Hc, g0 + 2 * Hc, be0 + 2 * Hc, m0 + 2 * Hc,
        v0 + 2 * Hc, cnt0, xp, N1c);

    // head0: logits + softmax -> d_out[0:48000], xb = [x0 | x_pool1]
    head0<<<N1c, 64, 0, stream>>>(xp, linW0, linb0, x_pool1, outp, xb);

    // ---- phase B: 3 GCN layers on N1 (fp32 vector GEMMs) ----
    agg17_gemm_bn<<<N1c, 256, 0, stream>>>(xb, rp1, csw, dinv1, W_in1, b1, g1, be1,
                                           m1, v1, hbbbf);
    agg_bf16<32, 4, false><<<4 * cdiv_i(N1c, 4), 256, 0, stream>>>(hbbbf, rp1, csw, dinv1, zbb, N1c);
    gemm_bn<256, true, false, true><<<dim3(cdiv_i(N1c, 64), 4), 256, 0, stream>>>(
        zbb, W_h1, b1 + Hc, g1 + Hc, be1 + Hc, m1 + Hc, v1 + Hc, nullptr, hbbbf, N1c);
    agg_bf16<32, 4, false><<<4 * cdiv_i(N1c, 4), 256, 0, stream>>>(hbbbf, rp1, csw, dinv1, zbb, N1c);

    // atomic-free 3000->16 reduction: 256-block partials, then head1 combines
    pool_b_partial<<<256, 256, 0, stream>>>(zbb, bpool, part, pcnt);
    head1<<<Bc, 256, 0, stream>>>(part, pcnt, W_h1 + Hc * Hc, b1 + 2 * Hc, g1 + 2 * Hc,
                                  be1 + 2 * Hc, m1 + 2 * Hc, v1 + 2 * Hc, linW1, linb1,
                                  outp);
}

// Round 13
// 474.251 us; speedup vs baseline: 1.3979x; 1.0248x over previous
//
#include <hip/hip_runtime.h>
#include <cstdint>
#include <cstddef>

// Problem constants
#define N0c 30000
#define F0c 128
#define Hc  256
#define Cc  16
#define N1c 3000
#define Bc  16
#define E0c 960000
#define E1c 48000
#define NALL 33000            // N0 + N1 (concatenated graphs)
#define EALL 1008000          // E0 + E1
#define EPSc 1e-5f
#define SLICE 188             // clusters per pool_b_partial slice (16*188 >= 3000)

static __host__ __device__ inline int cdiv_i(int a, int b) { return (a + b - 1) / b; }

// round-to-nearest-even fp32 -> bf16 (returns the 16 bf16 bits)
static __device__ inline unsigned short bfbits(float f) {
    unsigned u = __float_as_uint(f);
    return (unsigned short)((u + 0x7fffu + ((u >> 16) & 1u)) >> 16);
}

typedef short short8 __attribute__((ext_vector_type(8)));   // 8 bf16 = 4 VGPRs
typedef float floatx4 __attribute__((ext_vector_type(4)));

// ---------------- graph preprocessing (both graphs concatenated) ----------------

__global__ void count_deg_all(const int* __restrict__ dst0, const int* __restrict__ dst1,
                              int* __restrict__ deg) {
    int e = blockIdx.x * blockDim.x + threadIdx.x;
    if (e < E0c) atomicAdd(&deg[dst0[e]], 1);
    else if (e < EALL) atomicAdd(&deg[N0c + dst1[e - E0c]], 1);
}

// scan + dinv fused: dinv[i] = rsqrt(deg[i]+1)
__global__ void scan_block(const int* __restrict__ cnt, int n, int* __restrict__ rp,
                           int* __restrict__ blkSum, float* __restrict__ dinv) {
    __shared__ int sh[256];
    int t = threadIdx.x;
    int i = blockIdx.x * 256 + t;
    int v = (i < n) ? cnt[i] : 0;
    if (i < n) dinv[i] = rsqrtf((float)(v + 1));
    sh[t] = v; __syncthreads();
    for (int off = 1; off < 256; off <<= 1) {
        int add = (t >= off) ? sh[t - off] : 0;
        __syncthreads();
        sh[t] += add;
        __syncthreads();
    }
    if (i < n) rp[i] = sh[t] - v;
    if (t == 255) blkSum[blockIdx.x] = sh[255];
}

__global__ void scan_sums(const int* __restrict__ blkSum, int nb, int* __restrict__ blkOff,
                          int* __restrict__ rp, int n) {
    __shared__ int sh[256];
    int t = threadIdx.x;
    int v = (t < nb) ? blkSum[t] : 0;
    sh[t] = v; __syncthreads();
    for (int off = 1; off < 256; off <<= 1) {
        int add = (t >= off) ? sh[t - off] : 0;
        __syncthreads();
        sh[t] += add;
        __syncthreads();
    }
    blkOff[t] = sh[t] - v;
    if (t == 255) rp[n] = sh[255];
}

// ---------------- mega-prep: all post-scan independent work in ONE kernel ------
#define NB_FILL 3938
#define NB_RPF  129
#define NB_CVT  3750
#define NB_PW   386
#define NB_SEG  118

__global__ void megaprep(const int* __restrict__ src0, const int* __restrict__ dst0,
                         const int* __restrict__ src1, const int* __restrict__ dst1,
                         const int* __restrict__ rp, const int* __restrict__ blkOff,
                         int* __restrict__ tmp, const float* __restrict__ dinv,
                         unsigned* __restrict__ csw, int* __restrict__ rpf,
                         const float* __restrict__ x, unsigned short* __restrict__ xbf,
                         const float* __restrict__ W_in0, const float* __restrict__ W_h0,
                         const float* __restrict__ b0, const float* __restrict__ g0,
                         const float* __restrict__ be0, const float* __restrict__ m0,
                         const float* __restrict__ v0,
                         unsigned short* __restrict__ Wt0, unsigned short* __restrict__ Wt1,
                         float* __restrict__ sc0, float* __restrict__ sh0,
                         float* __restrict__ sc1, float* __restrict__ sh1,
                         const int* __restrict__ pool1, int* __restrict__ start0) {
    int bx = blockIdx.x, t = threadIdx.x;
    if (bx < NB_FILL) {
        int e = bx * 256 + t;
        if (e >= EALL) return;
        int s, d;
        if (e < E0c) { s = src0[e]; d = dst0[e]; }
        else         { s = N0c + src1[e - E0c]; d = N0c + dst1[e - E0c]; }
        int pos = rp[d] + blkOff[d >> 8] + atomicAdd(&tmp[d], 1);
        float w = dinv[s] * dinv[d];
        int sloc = (e < E0c) ? s : (s - N0c);
        csw[pos] = ((unsigned)bfbits(w) << 16) | (unsigned)sloc;
    } else if (bx < NB_FILL + NB_RPF) {
        int i = (bx - NB_FILL) * 256 + t;
        if (i < NALL) rpf[i] = rp[i] + blkOff[i >> 8];
        else if (i == NALL) rpf[NALL] = rp[NALL];   // total (already final)
    } else if (bx < NB_FILL + NB_RPF + NB_CVT) {
        int i = (bx - NB_FILL - NB_RPF) * 256 + t;  // float4 index
        if (i >= N0c * 32) return;
        float4 v = ((const float4*)x)[i];
        ushort4 o;
        o.x = bfbits(v.x); o.y = bfbits(v.y); o.z = bfbits(v.z); o.w = bfbits(v.w);
        ((ushort4*)xbf)[i] = o;
    } else if (bx < NB_FILL + NB_RPF + NB_CVT + NB_PW) {
        int pb = bx - NB_FILL - NB_RPF - NB_CVT;
        if (pb < 128) {
            int i = pb * 256 + t;
            int k = i >> 8, col = i & 255;
            Wt0[col * 128 + k] = bfbits(W_in0[i]);
        } else if (pb < 384) {
            int i = (pb - 128) * 256 + t;
            int k = i >> 8, col = i & 255;
            Wt1[col * 256 + k] = bfbits(W_h0[i]);
        } else if (pb == 384) {
            float s = g0[t] * rsqrtf(v0[t] + EPSc);
            sc0[t] = s;
            sh0[t] = (b0[t] - m0[t]) * s + be0[t];
        } else {
            int tt = t + 256;
            float s = g0[tt] * rsqrtf(v0[tt] + EPSc);
            sc1[t] = s;
            sh1[t] = (b0[tt] - m0[tt]) * s + be0[tt];
        }
    } else {
        int i = (bx - NB_FILL - NB_RPF - NB_CVT - NB_PW) * 256 + t;
        if (i > N0c) return;
        if (i == 0) {
            for (int c = 0; c <= pool1[0]; ++c) start0[c] = 0;
        } else if (i == N0c) {
            for (int c = pool1[N0c - 1] + 1; c <= N1c; ++c) start0[c] = N0c;
        } else {
            int a = pool1[i - 1], b = pool1[i];
            for (int c = a + 1; c <= b; ++c) start0[c] = i;
        }
    }
}

// ---------------- aggregation (bf16 gather, fp32 accumulate) ----------------

static __device__ inline void acc8(float a[8], float w, uint4 v) {
    a[0] += w * __uint_as_float(v.x << 16);
    a[1] += w * __uint_as_float(v.x & 0xffff0000u);
    a[2] += w * __uint_as_float(v.y << 16);
    a[3] += w * __uint_as_float(v.y & 0xffff0000u);
    a[4] += w * __uint_as_float(v.z << 16);
    a[5] += w * __uint_as_float(v.z & 0xffff0000u);
    a[6] += w * __uint_as_float(v.w << 16);
    a[7] += w * __uint_as_float(v.w & 0xffff0000u);
}

// r13: TWO nodes per wave, FOUR edge slots each (lane = ns*32 + par*8 + cl).
// Same 8 edges/wave-step and same gather widths as r12, but the cross-slot
// butterfly shrinks 3 levels->2 and is shared by 2 nodes: 48 -> 16 instrs per
// node-chunk (the butterfly was ~38% of wave instructions at VALUBusy 69%).
// NCHUNK chunks of 64 cols; chunk = blockIdx&(NCHUNK-1) keeps XCD pinning.
// 32-bit gather addressing; wave-uniform (max-over-pair) trip counts; unroll-2.
template <int RSU, int NCHUNK, bool OBF16>
__global__ __launch_bounds__(256) void agg_bf16(
    const unsigned short* __restrict__ x, const int* __restrict__ rp,
    const unsigned* __restrict__ csw, const float* __restrict__ dinv,
    void* __restrict__ zv, int N) {
    constexpr int SHIFT = (RSU == 32) ? 9 : 8;   // log2(row bytes)
    int b = blockIdx.x;
    int chunk = b & (NCHUNK - 1);
    int wave = threadIdx.x >> 6;
    int lane = threadIdx.x & 63;
    int ns = lane >> 5;                  // node sub (0/1)
    int par = (lane >> 3) & 3;           // edge slot (0..3)
    int cl = lane & 7;                   // 16B slice within 64-col chunk
    int node = (b / NCHUNK) * 8 + wave * 2 + ns;
    bool valid = node < N;
    int nclamp = valid ? node : 0;
    int c4 = chunk * 8 + cl;
    unsigned coff = (unsigned)c4 << 4;
    const char* xb = (const char*)x;
    float a[8] = {0.f, 0.f, 0.f, 0.f, 0.f, 0.f, 0.f, 0.f};
    int e0 = rp[nclamp];
    int e1 = valid ? rp[nclamp + 1] : e0;
    if (valid && par == 0) {             // self-loop term exactly once
        float di = dinv[node];
        uint4 v = *(const uint4*)(xb + (((unsigned)node << SHIFT) + coff));
        acc8(a, di * di, v);
    }
    int deg = e1 - e0;
    int myw = (deg + 31) >> 5;
    int nwin = max(__shfl(myw, 0, 64), __shfl(myw, 32, 64));   // wave-uniform
    int srcbase = lane & 32;
    for (int w = 0; w < nwin; ++w) {
        int base = e0 + w * 32;
        int avail = e1 - base;
        int cnt = avail < 0 ? 0 : (avail > 32 ? 32 : avail);   // per-half count
        unsigned my = 0;
        int li = lane & 31;
        if (li < cnt) my = csw[base + li];   // 32 edges per half in ONE load
        int mysteps = (cnt + 3) >> 2;
        int steps = max(__shfl(mysteps, 0, 64), __shfl(mysteps, 32, 64));
        int i = 0;
        for (; i + 1 < steps; i += 2) {      // 2 gathers in flight per half
            int idx0 = i * 4 + par, idx1 = idx0 + 4;
            unsigned ew0 = (unsigned)__shfl((int)my, srcbase + idx0, 64);
            unsigned ew1 = (unsigned)__shfl((int)my, srcbase + idx1, 64);
            if (idx0 < cnt) {
                uint4 v = *(const uint4*)(xb + (((ew0 & 0xffffu) << SHIFT) + coff));
                acc8(a, __uint_as_float(ew0 & 0xffff0000u), v);
            }
            if (idx1 < cnt) {
                uint4 v = *(const uint4*)(xb + (((ew1 & 0xffffu) << SHIFT) + coff));
                acc8(a, __uint_as_float(ew1 & 0xffff0000u), v);
            }
        }
        if (i < steps) {
            int idx = i * 4 + par;
            unsigned ew = (unsigned)__shfl((int)my, srcbase + idx, 64);
            if (idx < cnt) {
                uint4 v = *(const uint4*)(xb + (((ew & 0xffffu) << SHIFT) + coff));
                acc8(a, __uint_as_float(ew & 0xffff0000u), v);
            }
        }
    }
    // reduce across the 4 edge slots (2 levels, stays within each node half)
#pragma unroll
    for (int m = 8; m < 32; m <<= 1) {
#pragma unroll
        for (int k = 0; k < 8; ++k) a[k] += __shfl_xor(a[k], m, 64);
    }
    if (valid && par == 0) {
        if (OBF16) {
            uint4 o;
            o.x = (unsigned)bfbits(a[0]) | ((unsigned)bfbits(a[1]) << 16);
            o.y = (unsigned)bfbits(a[2]) | ((unsigned)bfbits(a[3]) << 16);
            o.z = (unsigned)bfbits(a[4]) | ((unsigned)bfbits(a[5]) << 16);
            o.w = (unsigned)bfbits(a[6]) | ((unsigned)bfbits(a[7]) << 16);
            ((uint4*)zv)[(size_t)node * RSU + c4] = o;
        } else {
            float4* zp = (float4*)zv + (size_t)node * (RSU * 2) + c4 * 2;
            zp[0] = make_float4(a[0], a[1], a[2], a[3]);
            zp[1] = make_float4(a[4], a[5], a[6], a[7]);
        }
    }
}

// ---------------- MFMA bf16 GEMM: (M x K)bf16 @ Wt(256 x K)bf16 -> bf16 out ----

template <int K>
__global__ __launch_bounds__(256) void gemm_mfma_bn(
    const unsigned short* __restrict__ A, const unsigned short* __restrict__ Wt,
    const float* __restrict__ sc, const float* __restrict__ sh,
    unsigned short* __restrict__ out, int M) {
    constexpr int LDS_S = 40;
    __shared__ unsigned short As[64 * LDS_S];
    __shared__ unsigned short Bs[256 * LDS_S];
    int tid = threadIdx.x;
    int w = tid >> 6, l = tid & 63;
    int quad = l >> 4, lm = l & 15;
    int row0 = blockIdx.x * 64;
    floatx4 acc[4][4];
#pragma unroll
    for (int i = 0; i < 4; ++i)
#pragma unroll
        for (int j = 0; j < 4; ++j) acc[i][j] = (floatx4){0.f, 0.f, 0.f, 0.f};

    int ar = tid >> 2;          // A staging: row 0..63
    int ac = (tid & 3) * 8;     // short offset 0,8,16,24

    for (int k0 = 0; k0 < K; k0 += 32) {
        uint4 av = make_uint4(0, 0, 0, 0);
        if (row0 + ar < M) av = *(const uint4*)(A + (size_t)(row0 + ar) * K + k0 + ac);
        *(uint4*)&As[ar * LDS_S + ac] = av;
#pragma unroll
        for (int c = 0; c < 4; ++c) {    // Bs: thread -> col tid, 4 k-chunks
            uint4 bv = *(const uint4*)(Wt + (size_t)tid * K + k0 + c * 8);
            *(uint4*)&Bs[tid * LDS_S + c * 8] = bv;
        }
        __syncthreads();
        short8 af[4], bf[4];
#pragma unroll
        for (int i = 0; i < 4; ++i)
            af[i] = *(const short8*)&As[(i * 16 + lm) * LDS_S + quad * 8];
#pragma unroll
        for (int j = 0; j < 4; ++j)
            bf[j] = *(const short8*)&Bs[(w * 64 + j * 16 + lm) * LDS_S + quad * 8];
#pragma unroll
        for (int i = 0; i < 4; ++i)
#pragma unroll
            for (int j = 0; j < 4; ++j)
                acc[i][j] = __builtin_amdgcn_mfma_f32_16x16x32_bf16(af[i], bf[j], acc[i][j], 0, 0, 0);
        __syncthreads();
    }
    // epilogue: C/D map col=lane&15, row=quad*4+reg [verified m89/m91]
#pragma unroll
    for (int j = 0; j < 4; ++j) {
        int col = w * 64 + j * 16 + lm;
        float s = sc[col], h = sh[col];
#pragma unroll
        for (int i = 0; i < 4; ++i) {
            int rb = row0 + i * 16 + quad * 4;
#pragma unroll
            for (int r = 0; r < 4; ++r) {
                int row = rb + r;
                if (row < M) {
                    float v = acc[i][j][r] * s + h;
                    v = fmaxf(v, 0.f);
                    out[(size_t)row * 256 + col] = bfbits(v);
                }
            }
        }
    }
}

// ---------------- fp32 vector GEMM (kept for small M=3000, precision-critical) --

template <int K, bool RELU, bool ZEROEMPTY, bool OBF16>
__global__ __launch_bounds__(256) void gemm_bn(
    const float* __restrict__ A, const float* __restrict__ W,
    const float* __restrict__ bias, const float* __restrict__ gam,
    const float* __restrict__ bet, const float* __restrict__ mu,
    const float* __restrict__ var, const int* __restrict__ cnt,
    void* __restrict__ outv, int M) {
    __shared__ __align__(16) float As[16][64];
    __shared__ __align__(16) float Bs[16][64];
    int tid = threadIdx.x;
    int tm = tid >> 4, tn = tid & 15;
    int row0 = blockIdx.x * 64, col0 = blockIdx.y * 64;
    float acc[4][4] = {};
    int ar = tid >> 2;
    int ak = (tid & 3) * 4;
    int bk = tid >> 4;
    int bn = (tid & 15) * 4;

    for (int kk = 0; kk < K; kk += 16) {
        float4 av = make_float4(0.f, 0.f, 0.f, 0.f);
        int grow = row0 + ar;
        if (grow < M) av = *(const float4*)(A + (size_t)grow * K + kk + ak);
        As[ak + 0][ar] = av.x;
        As[ak + 1][ar] = av.y;
        As[ak + 2][ar] = av.z;
        As[ak + 3][ar] = av.w;
        float4 bv = *(const float4*)(W + (size_t)(kk + bk) * 256 + col0 + bn);
        *(float4*)&Bs[bk][bn] = bv;
        __syncthreads();
#pragma unroll
        for (int k = 0; k < 16; ++k) {
            float4 a = *(const float4*)&As[k][tm * 4];
            float4 b = *(const float4*)&Bs[k][tn * 4];
            acc[0][0] += a.x * b.x; acc[0][1] += a.x * b.y; acc[0][2] += a.x * b.z; acc[0][3] += a.x * b.w;
            acc[1][0] += a.y * b.x; acc[1][1] += a.y * b.y; acc[1][2] += a.y * b.z; acc[1][3] += a.y * b.w;
            acc[2][0] += a.z * b.x; acc[2][1] += a.z * b.y; acc[2][2] += a.z * b.z; acc[2][3] += a.z * b.w;
            acc[3][0] += a.w * b.x; acc[3][1] += a.w * b.y; acc[3][2] += a.w * b.z; acc[3][3] += a.w * b.w;
        }
        __syncthreads();
    }
    float bcol[4], scol[4], mcol[4], ecol[4];
#pragma unroll
    for (int j = 0; j < 4; ++j) {
        int col = col0 + tn * 4 + j;
        bcol[j] = bias[col];
        scol[j] = gam[col] * rsqrtf(var[col] + EPSc);
        mcol[j] = mu[col];
        ecol[j] = bet[col];
    }
#pragma unroll
    for (int i = 0; i < 4; ++i) {
        int row = row0 + tm * 4 + i;
        if (row >= M) continue;
        bool zero = false;
        if (ZEROEMPTY) zero = (cnt[row] == 0);
        float r[4];
#pragma unroll
        for (int j = 0; j < 4; ++j) {
            float v = acc[i][j] + bcol[j];
            v = (v - mcol[j]) * scol[j] + ecol[j];
            if (RELU) v = fmaxf(v, 0.f);
            if (zero) v = 0.f;
            r[j] = v;
        }
        if (OBF16) {
            ushort4 o;
            o.x = bfbits(r[0]); o.y = bfbits(r[1]); o.z = bfbits(r[2]); o.w = bfbits(r[3]);
            *(ushort4*)((unsigned short*)outv + (size_t)row * 256 + col0 + tn * 4) = o;
        } else {
            float4 o = make_float4(r[0], r[1], r[2], r[3]);
            *(float4*)((float*)outv + (size_t)row * 256 + col0 + tn * 4) = o;
        }
    }
}

// fused: 17-wide aggregation (graph 1) + K=17 GEMM + BN + ReLU, bf16 out
__global__ void agg17_gemm_bn(const float* __restrict__ xb, const int* __restrict__ rp,
                              const unsigned* __restrict__ csw, const float* __restrict__ dinv,
                              const float* __restrict__ W, const float* __restrict__ bias,
                              const float* __restrict__ gam, const float* __restrict__ bet,
                              const float* __restrict__ mu, const float* __restrict__ var,
                              unsigned short* __restrict__ out) {
    int r = blockIdx.x, t = threadIdx.x;   // 256 threads
    __shared__ float zr[17];
    if (t < 17) {
        float di = dinv[r];
        float acc = di * di * xb[(size_t)r * 17 + t];
        int e0 = rp[r], e1 = rp[r + 1];
        for (int e = e0; e < e1; ++e) {
            unsigned ew = csw[e];
            acc += __uint_as_float(ew & 0xffff0000u) * xb[(size_t)(ew & 0xffffu) * 17 + t];
        }
        zr[t] = acc;
    }
    __syncthreads();
    float acc = bias[t];
#pragma unroll
    for (int k = 0; k < 17; ++k) acc += zr[k] * W[k * 256 + t];
    float s = gam[t] * rsqrtf(var[t] + EPSc);
    acc = (acc - mu[t]) * s + bet[t];
    acc = fmaxf(acc, 0.f);
    out[(size_t)r * 256 + t] = bfbits(acc);
}

// ---------------- pooling ----------------

__global__ void pool_mean(const float* __restrict__ z, const int* __restrict__ start,
                          const int* __restrict__ batch, float* __restrict__ p,
                          int* __restrict__ cnt_out, int* __restrict__ bpool) {
    int c = blockIdx.x, t = threadIdx.x;  // 64 threads
    int s = start[c], e = start[c + 1];
    int cnt = e - s;
    const float4* z4 = (const float4*)z;
    float ax = 0.f, ay = 0.f, az = 0.f, aw = 0.f;
    for (int i = s; i < e; ++i) {
        float4 v = z4[(size_t)i * 64 + t];
        ax += v.x; ay += v.y; az += v.z; aw += v.w;
    }
    float inv = 1.0f / (float)max(cnt, 1);
    ((float4*)p)[(size_t)c * 64 + t] = make_float4(ax * inv, ay * inv, az * inv, aw * inv);
    if (t == 0) {
        cnt_out[c] = cnt;
        int sb = 0;
        for (int i = s; i < e; ++i) sb += batch[i];
        bpool[c] = (int)rintf((float)sb * inv);
    }
}

// stage 1 of atomic-free 3000->16 reduction: 256 blocks = 16 graphs x 16 slices.
__global__ __launch_bounds__(256) void pool_b_partial(
    const float* __restrict__ zbb, const int* __restrict__ bpool,
    float* __restrict__ part, int* __restrict__ pcnt) {
    int b = blockIdx.x;          // 0..255
    int g = b & 15, s = b >> 4;
    int t = threadIdx.x;
    int i0 = s * SLICE;
    int n = min(N1c - i0, SLICE);
    __shared__ int bp[SLICE];
    for (int i = t; i < n; i += 256) bp[i] = bpool[i0 + i];
    __syncthreads();
    float acc = 0.f;
    int c = 0;
    for (int i = 0; i < n; ++i) {
        int hit = (bp[i] == g);
        float sel = hit ? 1.f : 0.f;
        acc += sel * zbb[(size_t)(i0 + i) * 256 + t];   // load NOT branch-gated
        c += hit;
    }
    part[(size_t)b * 256 + t] = acc;
    if (t == 0) pcnt[b] = c;
}

// ---------------- heads ----------------

__global__ void head0(const float* __restrict__ xp, const float* __restrict__ linW,
                      const float* __restrict__ linb, const float* __restrict__ xpool1,
                      float* __restrict__ outp, float* __restrict__ xb) {
    int r = blockIdx.x, t = threadIdx.x;  // 64 threads
    __shared__ float xr[256];
    __shared__ float lg[16];
    __shared__ float ex[16];
#pragma unroll
    for (int j = 0; j < 4; ++j) xr[t + 64 * j] = xp[(size_t)r * 256 + t + 64 * j];
    __syncthreads();
    if (t < 16) {
        float acc = linb[t];
        for (int k = 0; k < 256; ++k) acc += xr[k] * linW[k * 16 + t];
        lg[t] = acc;
    }
    __syncthreads();
    if (t < 16) {
        float mx = lg[0];
#pragma unroll
        for (int c = 1; c < 16; ++c) mx = fmaxf(mx, lg[c]);
        ex[t] = expf(lg[t] - mx);
    }
    __syncthreads();
    if (t < 16) {
        float sum = 0.f;
#pragma unroll
        for (int c = 0; c < 16; ++c) sum += ex[c];
        float pv = ex[t] / sum;
        outp[(size_t)r * 16 + t] = pv;
        xb[(size_t)r * 17 + t] = pv;
    }
    if (t == 16) xb[(size_t)r * 17 + 16] = xpool1[r];
}

// head1: sum 16 partials -> mean -> layer2 GEMM+BN -> logits -> softmax
__global__ void head1(const float* __restrict__ part, const int* __restrict__ pcnt,
                      const float* __restrict__ W, const float* __restrict__ bias,
                      const float* __restrict__ gam, const float* __restrict__ bet,
                      const float* __restrict__ mu, const float* __restrict__ var,
                      const float* __restrict__ linW, const float* __restrict__ linb,
                      float* __restrict__ outp) {
    int b = blockIdx.x, t = threadIdx.x;  // 16 blocks x 256 threads
    __shared__ float pr[256];
    __shared__ float yr[256];
    __shared__ float lg[16];
    __shared__ float ex[16];
    float acc0 = 0.f;
    int c = 0;
#pragma unroll
    for (int s = 0; s < 16; ++s) {
        int pb = s * 16 + b;
        acc0 += part[(size_t)pb * 256 + t];
        c += pcnt[pb];
    }
    float inv = 1.0f / (float)max(c, 1);
    pr[t] = acc0 * inv;
    __syncthreads();
    float acc = bias[t];
    for (int k = 0; k < 256; ++k) acc += pr[k] * W[k * 256 + t];
    float s = gam[t] * rsqrtf(var[t] + EPSc);
    acc = (acc - mu[t]) * s + bet[t];
    if (c == 0) acc = 0.f;
    yr[t] = acc;
    __syncthreads();
    if (t < 16) {
        float l = linb[t];
        for (int k = 0; k < 256; ++k) l += yr[k] * linW[k * 16 + t];
        lg[t] = l;
    }
    __syncthreads();
    if (t < 16) {
        float mx = lg[0];
#pragma unroll
        for (int cc = 1; cc < 16; ++cc) mx = fmaxf(mx, lg[cc]);
        ex[t] = expf(lg[t] - mx);
    }
    __syncthreads();
    if (t < 16) {
        float sum = 0.f;
#pragma unroll
        for (int cc = 0; cc < 16; ++cc) sum += ex[cc];
        outp[48000 + b * 16 + t] = ex[t] / sum;
    }
}

// ---------------- launch ----------------

extern "C" void kernel_launch(void* const* d_in, const int* in_sizes, int n_in,
                              void* d_out, int out_size, void* d_ws, size_t ws_size,
                              hipStream_t stream) {
    const float* x       = (const float*)d_in[0];
    const float* x_pool1 = (const float*)d_in[1];
    const float* W_in0   = (const float*)d_in[2];
    const float* W_h0    = (const float*)d_in[3];
    const float* b0      = (const float*)d_in[4];
    const float* g0      = (const float*)d_in[5];
    const float* be0     = (const float*)d_in[6];
    const float* m0      = (const float*)d_in[7];
    const float* v0      = (const float*)d_in[8];
    const float* W_in1   = (const float*)d_in[9];
    const float* W_h1    = (const float*)d_in[10];
    const float* b1      = (const float*)d_in[11];
    const float* g1      = (const float*)d_in[12];
    const float* be1     = (const float*)d_in[13];
    const float* m1      = (const float*)d_in[14];
    const float* v1      = (const float*)d_in[15];
    const float* linW0   = (const float*)d_in[16];
    const float* linb0   = (const float*)d_in[17];
    const float* linW1   = (const float*)d_in[18];
    const float* linb1   = (const float*)d_in[19];
    const int*   ei      = (const int*)d_in[20];
    const int*   batch   = (const int*)d_in[21];
    const int*   pool1   = (const int*)d_in[22];
    const int*   eip     = (const int*)d_in[23];
    float* outp = (float*)d_out;

    // carve workspace (256B-aligned); zero-init block FIRST (single memset)
    char* p = (char*)d_ws;
    auto carve = [&](size_t bytes) -> void* {
        void* r = (void*)p;
        p += (bytes + 255) & ~(size_t)255;
        return r;
    };
    int*   deg    = (int*)  carve((size_t)NALL * 4);   // zeroed
    int*   tmp    = (int*)  carve((size_t)NALL * 4);   // zeroed
    size_t zeroBytes = (size_t)((char*)p - (char*)deg);

    int*   rp     = (int*)  carve((size_t)(NALL + 1) * 4);
    int*   rpf    = (int*)  carve((size_t)(NALL + 1) * 4);
    float* dinv   = (float*)carve((size_t)NALL * 4);
    int*   blkSum = (int*)  carve(256 * 4);
    int*   blkOff = (int*)  carve(256 * 4);
    unsigned* csw = (unsigned*)carve((size_t)EALL * 4);
    // region1: [xbf | z0bf] aliased later by g1bf (15.36 MB total)
    unsigned short* xbf  = (unsigned short*)carve((size_t)N0c * 256 * 2);
    unsigned short* z0bf = xbf + (size_t)N0c * 128;
    unsigned short* g1bf = xbf;                         // alias (xbf,z0bf dead)
    // region2: [g0bf | z1bf] aliased later by bufA (30.72 MB total)
    unsigned short* g0bf = (unsigned short*)carve((size_t)N0c * 256 * 4);
    unsigned short* z1bf = g0bf + (size_t)N0c * 256;
    float* bufA = (float*)g0bf;                         // alias (g0bf,z1bf dead)

    unsigned short* Wt0 = (unsigned short*)carve((size_t)256 * 128 * 2);
    unsigned short* Wt1 = (unsigned short*)carve((size_t)256 * 256 * 2);
    float* sc0 = (float*)carve(256 * 4);
    float* sh0 = (float*)carve(256 * 4);
    float* sc1 = (float*)carve(256 * 4);
    float* sh1 = (float*)carve(256 * 4);

    int*   start0 = (int*)  carve((size_t)(N1c + 1) * 4);
    int*   cnt0   = (int*)  carve((size_t)N1c * 4);
    float* pmean  = (float*)carve((size_t)N1c * 256 * 4);
    float* xp     = (float*)carve((size_t)N1c * 256 * 4);
    float* xb     = (float*)carve((size_t)N1c * 17 * 4);
    int*   bpool  = (int*)  carve((size_t)N1c * 4);
    unsigned short* hbbbf = (unsigned short*)carve((size_t)N1c * 256 * 2);
    float* zbb    = (float*)carve((size_t)N1c * 256 * 4);
    float* part   = (float*)carve((size_t)256 * 256 * 4);
    int*   pcnt   = (int*)  carve((size_t)256 * 4);

    hipMemsetAsync(deg, 0, zeroBytes, stream);

    const int* src0 = ei;
    const int* dst0 = ei + E0c;
    const int* src1 = eip;
    const int* dst1 = eip + E1c;

    // ---- unified CSR build (4 dispatches) ----
    count_deg_all<<<cdiv_i(EALL, 256), 256, 0, stream>>>(dst0, dst1, deg);
    int nb = cdiv_i(NALL, 256);
    scan_block<<<nb, 256, 0, stream>>>(deg, NALL, rp, blkSum, dinv);
    scan_sums<<<1, 256, 0, stream>>>(blkSum, nb, blkOff, rp, NALL);
    megaprep<<<NB_FILL + NB_RPF + NB_CVT + NB_PW + NB_SEG, 256, 0, stream>>>(
        src0, dst0, src1, dst1, rp, blkOff, tmp, dinv, csw, rpf, x, xbf,
        W_in0, W_h0, b0, g0, be0, m0, v0, Wt0, Wt1, sc0, sh0, sc1, sh1,
        pool1, start0);

    const int*   rp1   = rpf + N0c;
    const float* dinv1 = dinv + N0c;

    // ---- phase A: 3 GCN layers on N0 (layers 0/1: bf16 MFMA path) ----
    agg_bf16<16, 2, true><<<2 * cdiv_i(N0c, 8), 256, 0, stream>>>(xbf, rpf, csw, dinv, z0bf, N0c);
    gemm_mfma_bn<128><<<cdiv_i(N0c, 64), 256, 0, stream>>>(z0bf, Wt0, sc0, sh0, g0bf, N0c);
    agg_bf16<32, 4, true><<<4 * cdiv_i(N0c, 8), 256, 0, stream>>>(g0bf, rpf, csw, dinv, z1bf, N0c);
    gemm_mfma_bn<256><<<cdiv_i(N0c, 64), 256, 0, stream>>>(z1bf, Wt1, sc1, sh1, g1bf, N0c);
    agg_bf16<32, 4, false><<<4 * cdiv_i(N0c, 8), 256, 0, stream>>>(g1bf, rpf, csw, dinv, bufA, N0c);

    // layer 2: pool BEFORE GEMM (affine reorder); fp32 vector GEMM (precision)
    pool_mean<<<N1c, 64, 0, stream>>>(bufA, start0, batch, pmean, cnt0, bpool);
    gemm_bn<256, false, true, false><<<dim3(cdiv_i(N1c, 64), 4), 256, 0, stream>>>(
        pmean, W_h0 + Hc * Hc, b0 + 2 * Hc, g0 + 2 * Hc, be0 + 2 * Hc, m0 + 2 * Hc,
        v0 + 2 * Hc, cnt0, xp, N1c);

    // head0: logits + softmax -> d_out[0:48000], xb = [x0 | x_pool1]
    head0<<<N1c, 64, 0, stream>>>(xp, linW0, linb0, x_pool1, outp, xb);

    // ---- phase B: 3 GCN layers on N1 (fp32 vector GEMMs) ----
    agg17_gemm_bn<<<N1c, 256, 0, stream>>>(xb, rp1, csw, dinv1, W_in1, b1, g1, be1,
                                           m1, v1, hbbbf);
    agg_bf16<32, 4, false><<<4 * cdiv_i(N1c, 8), 256, 0, stream>>>(hbbbf, rp1, csw, dinv1, zbb, N1c);
    gemm_bn<256, true, false, true><<<dim3(cdiv_i(N1c, 64), 4), 256, 0, stream>>>(
        zbb, W_h1, b1 + Hc, g1 + Hc, be1 + Hc, m1 + Hc, v1 + Hc, nullptr, hbbbf, N1c);
    agg_bf16<32, 4, false><<<4 * cdiv_i(N1c, 8), 256, 0, stream>>>(hbbbf, rp1, csw, dinv1, zbb, N1c);

    // atomic-free 3000->16 reduction: 256-block partials, then head1 combines
    pool_b_partial<<<256, 256, 0, stream>>>(zbb, bpool, part, pcnt);
    head1<<<Bc, 256, 0, stream>>>(part, pcnt, W_h1 + Hc * Hc, b1 + 2 * Hc, g1 + 2 * Hc,
                                  be1 + 2 * Hc, m1 + 2 * Hc, v1 + 2 * Hc, linW1, linb1,
                                  outp);
}

// Round 14
// 444.702 us; speedup vs baseline: 1.4908x; 1.0664x over previous
//
#include <hip/hip_runtime.h>
#include <cstdint>
#include <cstddef>

// Problem constants
#define N0c 30000
#define F0c 128
#define Hc  256
#define Cc  16
#define N1c 3000
#define Bc  16
#define E0c 960000
#define E1c 48000
#define NALL 33000            // N0 + N1 (concatenated graphs)
#define EALL 1008000          // E0 + E1
#define EPSc 1e-5f
#define SLICE 188             // clusters per pool_b_partial slice (16*188 >= 3000)

static __host__ __device__ inline int cdiv_i(int a, int b) { return (a + b - 1) / b; }

// round-to-nearest-even fp32 -> bf16 (returns the 16 bf16 bits)
static __device__ inline unsigned short bfbits(float f) {
    unsigned u = __float_as_uint(f);
    return (unsigned short)((u + 0x7fffu + ((u >> 16) & 1u)) >> 16);
}

typedef short short8 __attribute__((ext_vector_type(8)));   // 8 bf16 = 4 VGPRs
typedef float floatx4 __attribute__((ext_vector_type(4)));

// ---------------- prep1: degree+rank histogram + all scan-independent work ----
// The counting atomic's RETURN VALUE is the edge's rank within its dst row ->
// the fill pass needs no atomics (r13 post-mortem: 2M global atomics ~100us).
// Sections: [0,P1_E) rank/deg; [+P1_CVT) x->bf16; [+P1_PW) weight prep;
// [+P1_SEG) seg_starts. Atomic-latency waves co-schedule with BW-bound waves.
#define P1_E   3938
#define P1_CVT 3750
#define P1_PW  386
#define P1_SEG 118

__global__ void prep1(const int* __restrict__ dst0, const int* __restrict__ dst1,
                      int* __restrict__ deg, unsigned short* __restrict__ rank,
                      const float* __restrict__ x, unsigned short* __restrict__ xbf,
                      const float* __restrict__ W_in0, const float* __restrict__ W_h0,
                      const float* __restrict__ b0, const float* __restrict__ g0,
                      const float* __restrict__ be0, const float* __restrict__ m0,
                      const float* __restrict__ v0,
                      unsigned short* __restrict__ Wt0, unsigned short* __restrict__ Wt1,
                      float* __restrict__ sc0, float* __restrict__ sh0,
                      float* __restrict__ sc1, float* __restrict__ sh1,
                      const int* __restrict__ pool1, int* __restrict__ start0) {
    int bx = blockIdx.x, t = threadIdx.x;
    if (bx < P1_E) {
        int e = bx * 256 + t;
        if (e >= EALL) return;
        int d = (e < E0c) ? dst0[e] : (N0c + dst1[e - E0c]);
        rank[e] = (unsigned short)atomicAdd(&deg[d], 1);   // coalesced u16 store
    } else if (bx < P1_E + P1_CVT) {
        int i = (bx - P1_E) * 256 + t;              // float4 index
        if (i >= N0c * 32) return;
        float4 v = ((const float4*)x)[i];
        ushort4 o;
        o.x = bfbits(v.x); o.y = bfbits(v.y); o.z = bfbits(v.z); o.w = bfbits(v.w);
        ((ushort4*)xbf)[i] = o;
    } else if (bx < P1_E + P1_CVT + P1_PW) {
        int pb = bx - P1_E - P1_CVT;
        if (pb < 128) {
            int i = pb * 256 + t;
            int k = i >> 8, col = i & 255;
            Wt0[col * 128 + k] = bfbits(W_in0[i]);
        } else if (pb < 384) {
            int i = (pb - 128) * 256 + t;
            int k = i >> 8, col = i & 255;
            Wt1[col * 256 + k] = bfbits(W_h0[i]);
        } else if (pb == 384) {
            float s = g0[t] * rsqrtf(v0[t] + EPSc);
            sc0[t] = s;
            sh0[t] = (b0[t] - m0[t]) * s + be0[t];
        } else {
            int tt = t + 256;
            float s = g0[tt] * rsqrtf(v0[tt] + EPSc);
            sc1[t] = s;
            sh1[t] = (b0[tt] - m0[tt]) * s + be0[tt];
        }
    } else {
        int i = (bx - P1_E - P1_CVT - P1_PW) * 256 + t;
        if (i > N0c) return;
        if (i == 0) {
            for (int c = 0; c <= pool1[0]; ++c) start0[c] = 0;
        } else if (i == N0c) {
            for (int c = pool1[N0c - 1] + 1; c <= N1c; ++c) start0[c] = N0c;
        } else {
            int a = pool1[i - 1], b = pool1[i];
            for (int c = a + 1; c <= b; ++c) start0[c] = i;
        }
    }
}

// scan + dinv fused: dinv[i] = rsqrt(deg[i]+1)
__global__ void scan_block(const int* __restrict__ cnt, int n, int* __restrict__ rp,
                           int* __restrict__ blkSum, float* __restrict__ dinv) {
    __shared__ int sh[256];
    int t = threadIdx.x;
    int i = blockIdx.x * 256 + t;
    int v = (i < n) ? cnt[i] : 0;
    if (i < n) dinv[i] = rsqrtf((float)(v + 1));
    sh[t] = v; __syncthreads();
    for (int off = 1; off < 256; off <<= 1) {
        int add = (t >= off) ? sh[t - off] : 0;
        __syncthreads();
        sh[t] += add;
        __syncthreads();
    }
    if (i < n) rp[i] = sh[t] - v;
    if (t == 255) blkSum[blockIdx.x] = sh[255];
}

__global__ void scan_sums(const int* __restrict__ blkSum, int nb, int* __restrict__ blkOff,
                          int* __restrict__ rp, int n) {
    __shared__ int sh[256];
    int t = threadIdx.x;
    int v = (t < nb) ? blkSum[t] : 0;
    sh[t] = v; __syncthreads();
    for (int off = 1; off < 256; off <<= 1) {
        int add = (t >= off) ? sh[t - off] : 0;
        __syncthreads();
        sh[t] += add;
        __syncthreads();
    }
    blkOff[t] = sh[t] - v;
    if (t == 255) rp[n] = sh[255];
}

// ---------------- prep2: ATOMIC-FREE csr fill + final row pointers ------------
#define P2_FILL 3938
#define P2_RPF  129

__global__ void prep2(const int* __restrict__ src0, const int* __restrict__ dst0,
                      const int* __restrict__ src1, const int* __restrict__ dst1,
                      const int* __restrict__ rp, const int* __restrict__ blkOff,
                      const unsigned short* __restrict__ rank,
                      const float* __restrict__ dinv, unsigned* __restrict__ csw,
                      int* __restrict__ rpf) {
    int bx = blockIdx.x, t = threadIdx.x;
    if (bx < P2_FILL) {
        int e = bx * 256 + t;
        if (e >= EALL) return;
        int s, d;
        if (e < E0c) { s = src0[e]; d = dst0[e]; }
        else         { s = N0c + src1[e - E0c]; d = N0c + dst1[e - E0c]; }
        int pos = rp[d] + blkOff[d >> 8] + (int)rank[e];
        float w = dinv[s] * dinv[d];
        int sloc = (e < E0c) ? s : (s - N0c);
        csw[pos] = ((unsigned)bfbits(w) << 16) | (unsigned)sloc;
    } else {
        int i = (bx - P2_FILL) * 256 + t;
        if (i < NALL) rpf[i] = rp[i] + blkOff[i >> 8];
        else if (i == NALL) rpf[NALL] = rp[NALL];   // total (already final)
    }
}

// ---------------- aggregation (bf16 gather, fp32 accumulate) ----------------

static __device__ inline void acc8(float a[8], float w, uint4 v) {
    a[0] += w * __uint_as_float(v.x << 16);
    a[1] += w * __uint_as_float(v.x & 0xffff0000u);
    a[2] += w * __uint_as_float(v.y << 16);
    a[3] += w * __uint_as_float(v.y & 0xffff0000u);
    a[4] += w * __uint_as_float(v.z << 16);
    a[5] += w * __uint_as_float(v.z & 0xffff0000u);
    a[6] += w * __uint_as_float(v.w << 16);
    a[7] += w * __uint_as_float(v.w & 0xffff0000u);
}

// TWO nodes per wave, FOUR edge slots each (lane = ns*32 + par*8 + cl).
// NCHUNK chunks of 64 cols; chunk = blockIdx&(NCHUNK-1) keeps XCD pinning.
// 32-bit gather addressing; wave-uniform (max-over-pair) trip counts; unroll-2.
template <int RSU, int NCHUNK, bool OBF16>
__global__ __launch_bounds__(256) void agg_bf16(
    const unsigned short* __restrict__ x, const int* __restrict__ rp,
    const unsigned* __restrict__ csw, const float* __restrict__ dinv,
    void* __restrict__ zv, int N) {
    constexpr int SHIFT = (RSU == 32) ? 9 : 8;   // log2(row bytes)
    int b = blockIdx.x;
    int chunk = b & (NCHUNK - 1);
    int wave = threadIdx.x >> 6;
    int lane = threadIdx.x & 63;
    int ns = lane >> 5;                  // node sub (0/1)
    int par = (lane >> 3) & 3;           // edge slot (0..3)
    int cl = lane & 7;                   // 16B slice within 64-col chunk
    int node = (b / NCHUNK) * 8 + wave * 2 + ns;
    bool valid = node < N;
    int nclamp = valid ? node : 0;
    int c4 = chunk * 8 + cl;
    unsigned coff = (unsigned)c4 << 4;
    const char* xb = (const char*)x;
    float a[8] = {0.f, 0.f, 0.f, 0.f, 0.f, 0.f, 0.f, 0.f};
    int e0 = rp[nclamp];
    int e1 = valid ? rp[nclamp + 1] : e0;
    if (valid && par == 0) {             // self-loop term exactly once
        float di = dinv[node];
        uint4 v = *(const uint4*)(xb + (((unsigned)node << SHIFT) + coff));
        acc8(a, di * di, v);
    }
    int deg = e1 - e0;
    int myw = (deg + 31) >> 5;
    int nwin = max(__shfl(myw, 0, 64), __shfl(myw, 32, 64));   // wave-uniform
    int srcbase = lane & 32;
    for (int w = 0; w < nwin; ++w) {
        int base = e0 + w * 32;
        int avail = e1 - base;
        int cnt = avail < 0 ? 0 : (avail > 32 ? 32 : avail);   // per-half count
        unsigned my = 0;
        int li = lane & 31;
        if (li < cnt) my = csw[base + li];   // 32 edges per half in ONE load
        int mysteps = (cnt + 3) >> 2;
        int steps = max(__shfl(mysteps, 0, 64), __shfl(mysteps, 32, 64));
        int i = 0;
        for (; i + 1 < steps; i += 2) {      // 2 gathers in flight per half
            int idx0 = i * 4 + par, idx1 = idx0 + 4;
            unsigned ew0 = (unsigned)__shfl((int)my, srcbase + idx0, 64);
            unsigned ew1 = (unsigned)__shfl((int)my, srcbase + idx1, 64);
            if (idx0 < cnt) {
                uint4 v = *(const uint4*)(xb + (((ew0 & 0xffffu) << SHIFT) + coff));
                acc8(a, __uint_as_float(ew0 & 0xffff0000u), v);
            }
            if (idx1 < cnt) {
                uint4 v = *(const uint4*)(xb + (((ew1 & 0xffffu) << SHIFT) + coff));
                acc8(a, __uint_as_float(ew1 & 0xffff0000u), v);
            }
        }
        if (i < steps) {
            int idx = i * 4 + par;
            unsigned ew = (unsigned)__shfl((int)my, srcbase + idx, 64);
            if (idx < cnt) {
                uint4 v = *(const uint4*)(xb + (((ew & 0xffffu) << SHIFT) + coff));
                acc8(a, __uint_as_float(ew & 0xffff0000u), v);
            }
        }
    }
    // reduce across the 4 edge slots (2 levels, stays within each node half)
#pragma unroll
    for (int m = 8; m < 32; m <<= 1) {
#pragma unroll
        for (int k = 0; k < 8; ++k) a[k] += __shfl_xor(a[k], m, 64);
    }
    if (valid && par == 0) {
        if (OBF16) {
            uint4 o;
            o.x = (unsigned)bfbits(a[0]) | ((unsigned)bfbits(a[1]) << 16);
            o.y = (unsigned)bfbits(a[2]) | ((unsigned)bfbits(a[3]) << 16);
            o.z = (unsigned)bfbits(a[4]) | ((unsigned)bfbits(a[5]) << 16);
            o.w = (unsigned)bfbits(a[6]) | ((unsigned)bfbits(a[7]) << 16);
            ((uint4*)zv)[(size_t)node * RSU + c4] = o;
        } else {
            float4* zp = (float4*)zv + (size_t)node * (RSU * 2) + c4 * 2;
            zp[0] = make_float4(a[0], a[1], a[2], a[3]);
            zp[1] = make_float4(a[4], a[5], a[6], a[7]);
        }
    }
}

// ---------------- MFMA bf16 GEMM: (M x K)bf16 @ Wt(256 x K)bf16 -> bf16 out ----

template <int K>
__global__ __launch_bounds__(256) void gemm_mfma_bn(
    const unsigned short* __restrict__ A, const unsigned short* __restrict__ Wt,
    const float* __restrict__ sc, const float* __restrict__ sh,
    unsigned short* __restrict__ out, int M) {
    constexpr int LDS_S = 40;
    __shared__ unsigned short As[64 * LDS_S];
    __shared__ unsigned short Bs[256 * LDS_S];
    int tid = threadIdx.x;
    int w = tid >> 6, l = tid & 63;
    int quad = l >> 4, lm = l & 15;
    int row0 = blockIdx.x * 64;
    floatx4 acc[4][4];
#pragma unroll
    for (int i = 0; i < 4; ++i)
#pragma unroll
        for (int j = 0; j < 4; ++j) acc[i][j] = (floatx4){0.f, 0.f, 0.f, 0.f};

    int ar = tid >> 2;          // A staging: row 0..63
    int ac = (tid & 3) * 8;     // short offset 0,8,16,24

    for (int k0 = 0; k0 < K; k0 += 32) {
        uint4 av = make_uint4(0, 0, 0, 0);
        if (row0 + ar < M) av = *(const uint4*)(A + (size_t)(row0 + ar) * K + k0 + ac);
        *(uint4*)&As[ar * LDS_S + ac] = av;
#pragma unroll
        for (int c = 0; c < 4; ++c) {    // Bs: thread -> col tid, 4 k-chunks
            uint4 bv = *(const uint4*)(Wt + (size_t)tid * K + k0 + c * 8);
            *(uint4*)&Bs[tid * LDS_S + c * 8] = bv;
        }
        __syncthreads();
        short8 af[4], bf[4];
#pragma unroll
        for (int i = 0; i < 4; ++i)
            af[i] = *(const short8*)&As[(i * 16 + lm) * LDS_S + quad * 8];
#pragma unroll
        for (int j = 0; j < 4; ++j)
            bf[j] = *(const short8*)&Bs[(w * 64 + j * 16 + lm) * LDS_S + quad * 8];
#pragma unroll
        for (int i = 0; i < 4; ++i)
#pragma unroll
            for (int j = 0; j < 4; ++j)
                acc[i][j] = __builtin_amdgcn_mfma_f32_16x16x32_bf16(af[i], bf[j], acc[i][j], 0, 0, 0);
        __syncthreads();
    }
    // epilogue: C/D map col=lane&15, row=quad*4+reg [verified m89/m91]
#pragma unroll
    for (int j = 0; j < 4; ++j) {
        int col = w * 64 + j * 16 + lm;
        float s = sc[col], h = sh[col];
#pragma unroll
        for (int i = 0; i < 4; ++i) {
            int rb = row0 + i * 16 + quad * 4;
#pragma unroll
            for (int r = 0; r < 4; ++r) {
                int row = rb + r;
                if (row < M) {
                    float v = acc[i][j][r] * s + h;
                    v = fmaxf(v, 0.f);
                    out[(size_t)row * 256 + col] = bfbits(v);
                }
            }
        }
    }
}

// ---------------- fp32 vector GEMM (kept for small M=3000, precision-critical) --

template <int K, bool RELU, bool ZEROEMPTY, bool OBF16>
__global__ __launch_bounds__(256) void gemm_bn(
    const float* __restrict__ A, const float* __restrict__ W,
    const float* __restrict__ bias, const float* __restrict__ gam,
    const float* __restrict__ bet, const float* __restrict__ mu,
    const float* __restrict__ var, const int* __restrict__ cnt,
    void* __restrict__ outv, int M) {
    __shared__ __align__(16) float As[16][64];
    __shared__ __align__(16) float Bs[16][64];
    int tid = threadIdx.x;
    int tm = tid >> 4, tn = tid & 15;
    int row0 = blockIdx.x * 64, col0 = blockIdx.y * 64;
    float acc[4][4] = {};
    int ar = tid >> 2;
    int ak = (tid & 3) * 4;
    int bk = tid >> 4;
    int bn = (tid & 15) * 4;

    for (int kk = 0; kk < K; kk += 16) {
        float4 av = make_float4(0.f, 0.f, 0.f, 0.f);
        int grow = row0 + ar;
        if (grow < M) av = *(const float4*)(A + (size_t)grow * K + kk + ak);
        As[ak + 0][ar] = av.x;
        As[ak + 1][ar] = av.y;
        As[ak + 2][ar] = av.z;
        As[ak + 3][ar] = av.w;
        float4 bv = *(const float4*)(W + (size_t)(kk + bk) * 256 + col0 + bn);
        *(float4*)&Bs[bk][bn] = bv;
        __syncthreads();
#pragma unroll
        for (int k = 0; k < 16; ++k) {
            float4 a = *(const float4*)&As[k][tm * 4];
            float4 b = *(const float4*)&Bs[k][tn * 4];
            acc[0][0] += a.x * b.x; acc[0][1] += a.x * b.y; acc[0][2] += a.x * b.z; acc[0][3] += a.x * b.w;
            acc[1][0] += a.y * b.x; acc[1][1] += a.y * b.y; acc[1][2] += a.y * b.z; acc[1][3] += a.y * b.w;
            acc[2][0] += a.z * b.x; acc[2][1] += a.z * b.y; acc[2][2] += a.z * b.z; acc[2][3] += a.z * b.w;
            acc[3][0] += a.w * b.x; acc[3][1] += a.w * b.y; acc[3][2] += a.w * b.z; acc[3][3] += a.w * b.w;
        }
        __syncthreads();
    }
    float bcol[4], scol[4], mcol[4], ecol[4];
#pragma unroll
    for (int j = 0; j < 4; ++j) {
        int col = col0 + tn * 4 + j;
        bcol[j] = bias[col];
        scol[j] = gam[col] * rsqrtf(var[col] + EPSc);
        mcol[j] = mu[col];
        ecol[j] = bet[col];
    }
#pragma unroll
    for (int i = 0; i < 4; ++i) {
        int row = row0 + tm * 4 + i;
        if (row >= M) continue;
        bool zero = false;
        if (ZEROEMPTY) zero = (cnt[row] == 0);
        float r[4];
#pragma unroll
        for (int j = 0; j < 4; ++j) {
            float v = acc[i][j] + bcol[j];
            v = (v - mcol[j]) * scol[j] + ecol[j];
            if (RELU) v = fmaxf(v, 0.f);
            if (zero) v = 0.f;
            r[j] = v;
        }
        if (OBF16) {
            ushort4 o;
            o.x = bfbits(r[0]); o.y = bfbits(r[1]); o.z = bfbits(r[2]); o.w = bfbits(r[3]);
            *(ushort4*)((unsigned short*)outv + (size_t)row * 256 + col0 + tn * 4) = o;
        } else {
            float4 o = make_float4(r[0], r[1], r[2], r[3]);
            *(float4*)((float*)outv + (size_t)row * 256 + col0 + tn * 4) = o;
        }
    }
}

// fused: 17-wide aggregation (graph 1) + K=17 GEMM + BN + ReLU, bf16 out
__global__ void agg17_gemm_bn(const float* __restrict__ xb, const int* __restrict__ rp,
                              const unsigned* __restrict__ csw, const float* __restrict__ dinv,
                              const float* __restrict__ W, const float* __restrict__ bias,
                              const float* __restrict__ gam, const float* __restrict__ bet,
                              const float* __restrict__ mu, const float* __restrict__ var,
                              unsigned short* __restrict__ out) {
    int r = blockIdx.x, t = threadIdx.x;   // 256 threads
    __shared__ float zr[17];
    if (t < 17) {
        float di = dinv[r];
        float acc = di * di * xb[(size_t)r * 17 + t];
        int e0 = rp[r], e1 = rp[r + 1];
        for (int e = e0; e < e1; ++e) {
            unsigned ew = csw[e];
            acc += __uint_as_float(ew & 0xffff0000u) * xb[(size_t)(ew & 0xffffu) * 17 + t];
        }
        zr[t] = acc;
    }
    __syncthreads();
    float acc = bias[t];
#pragma unroll
    for (int k = 0; k < 17; ++k) acc += zr[k] * W[k * 256 + t];
    float s = gam[t] * rsqrtf(var[t] + EPSc);
    acc = (acc - mu[t]) * s + bet[t];
    acc = fmaxf(acc, 0.f);
    out[(size_t)r * 256 + t] = bfbits(acc);
}

// ---------------- pooling ----------------

__global__ void pool_mean(const float* __restrict__ z, const int* __restrict__ start,
                          const int* __restrict__ batch, float* __restrict__ p,
                          int* __restrict__ cnt_out, int* __restrict__ bpool) {
    int c = blockIdx.x, t = threadIdx.x;  // 64 threads
    int s = start[c], e = start[c + 1];
    int cnt = e - s;
    const float4* z4 = (const float4*)z;
    float ax = 0.f, ay = 0.f, az = 0.f, aw = 0.f;
    for (int i = s; i < e; ++i) {
        float4 v = z4[(size_t)i * 64 + t];
        ax += v.x; ay += v.y; az += v.z; aw += v.w;
    }
    float inv = 1.0f / (float)max(cnt, 1);
    ((float4*)p)[(size_t)c * 64 + t] = make_float4(ax * inv, ay * inv, az * inv, aw * inv);
    if (t == 0) {
        cnt_out[c] = cnt;
        int sb = 0;
        for (int i = s; i < e; ++i) sb += batch[i];
        bpool[c] = (int)rintf((float)sb * inv);
    }
}

// stage 1 of atomic-free 3000->16 reduction: 256 blocks = 16 graphs x 16 slices.
__global__ __launch_bounds__(256) void pool_b_partial(
    const float* __restrict__ zbb, const int* __restrict__ bpool,
    float* __restrict__ part, int* __restrict__ pcnt) {
    int b = blockIdx.x;          // 0..255
    int g = b & 15, s = b >> 4;
    int t = threadIdx.x;
    int i0 = s * SLICE;
    int n = min(N1c - i0, SLICE);
    __shared__ int bp[SLICE];
    for (int i = t; i < n; i += 256) bp[i] = bpool[i0 + i];
    __syncthreads();
    float acc = 0.f;
    int c = 0;
    for (int i = 0; i < n; ++i) {
        int hit = (bp[i] == g);
        float sel = hit ? 1.f : 0.f;
        acc += sel * zbb[(size_t)(i0 + i) * 256 + t];   // load NOT branch-gated
        c += hit;
    }
    part[(size_t)b * 256 + t] = acc;
    if (t == 0) pcnt[b] = c;
}

// ---------------- heads ----------------

__global__ void head0(const float* __restrict__ xp, const float* __restrict__ linW,
                      const float* __restrict__ linb, const float* __restrict__ xpool1,
                      float* __restrict__ outp, float* __restrict__ xb) {
    int r = blockIdx.x, t = threadIdx.x;  // 64 threads
    __shared__ float xr[256];
    __shared__ float lg[16];
    __shared__ float ex[16];
#pragma unroll
    for (int j = 0; j < 4; ++j) xr[t + 64 * j] = xp[(size_t)r * 256 + t + 64 * j];
    __syncthreads();
    if (t < 16) {
        float acc = linb[t];
        for (int k = 0; k < 256; ++k) acc += xr[k] * linW[k * 16 + t];
        lg[t] = acc;
    }
    __syncthreads();
    if (t < 16) {
        float mx = lg[0];
#pragma unroll
        for (int c = 1; c < 16; ++c) mx = fmaxf(mx, lg[c]);
        ex[t] = expf(lg[t] - mx);
    }
    __syncthreads();
    if (t < 16) {
        float sum = 0.f;
#pragma unroll
        for (int c = 0; c < 16; ++c) sum += ex[c];
        float pv = ex[t] / sum;
        outp[(size_t)r * 16 + t] = pv;
        xb[(size_t)r * 17 + t] = pv;
    }
    if (t == 16) xb[(size_t)r * 17 + 16] = xpool1[r];
}

// head1: sum 16 partials -> mean -> layer2 GEMM+BN -> logits -> softmax
__global__ void head1(const float* __restrict__ part, const int* __restrict__ pcnt,
                      const float* __restrict__ W, const float* __restrict__ bias,
                      const float* __restrict__ gam, const float* __restrict__ bet,
                      const float* __restrict__ mu, const float* __restrict__ var,
                      const float* __restrict__ linW, const float* __restrict__ linb,
                      float* __restrict__ outp) {
    int b = blockIdx.x, t = threadIdx.x;  // 16 blocks x 256 threads
    __shared__ float pr[256];
    __shared__ float yr[256];
    __shared__ float lg[16];
    __shared__ float ex[16];
    float acc0 = 0.f;
    int c = 0;
#pragma unroll
    for (int s = 0; s < 16; ++s) {
        int pb = s * 16 + b;
        acc0 += part[(size_t)pb * 256 + t];
        c += pcnt[pb];
    }
    float inv = 1.0f / (float)max(c, 1);
    pr[t] = acc0 * inv;
    __syncthreads();
    float acc = bias[t];
    for (int k = 0; k < 256; ++k) acc += pr[k] * W[k * 256 + t];
    float s = gam[t] * rsqrtf(var[t] + EPSc);
    acc = (acc - mu[t]) * s + bet[t];
    if (c == 0) acc = 0.f;
    yr[t] = acc;
    __syncthreads();
    if (t < 16) {
        float l = linb[t];
        for (int k = 0; k < 256; ++k) l += yr[k] * linW[k * 16 + t];
        lg[t] = l;
    }
    __syncthreads();
    if (t < 16) {
        float mx = lg[0];
#pragma unroll
        for (int cc = 1; cc < 16; ++cc) mx = fmaxf(mx, lg[cc]);
        ex[t] = expf(lg[t] - mx);
    }
    __syncthreads();
    if (t < 16) {
        float sum = 0.f;
#pragma unroll
        for (int cc = 0; cc < 16; ++cc) sum += ex[cc];
        outp[48000 + b * 16 + t] = ex[t] / sum;
    }
}

// ---------------- launch ----------------

extern "C" void kernel_launch(void* const* d_in, const int* in_sizes, int n_in,
                              void* d_out, int out_size, void* d_ws, size_t ws_size,
                              hipStream_t stream) {
    const float* x       = (const float*)d_in[0];
    const float* x_pool1 = (const float*)d_in[1];
    const float* W_in0   = (const float*)d_in[2];
    const float* W_h0    = (const float*)d_in[3];
    const float* b0      = (const float*)d_in[4];
    const float* g0      = (const float*)d_in[5];
    const float* be0     = (const float*)d_in[6];
    const float* m0      = (const float*)d_in[7];
    const float* v0      = (const float*)d_in[8];
    const float* W_in1   = (const float*)d_in[9];
    const float* W_h1    = (const float*)d_in[10];
    const float* b1      = (const float*)d_in[11];
    const float* g1      = (const float*)d_in[12];
    const float* be1     = (const float*)d_in[13];
    const float* m1      = (const float*)d_in[14];
    const float* v1      = (const float*)d_in[15];
    const float* linW0   = (const float*)d_in[16];
    const float* linb0   = (const float*)d_in[17];
    const float* linW1   = (const float*)d_in[18];
    const float* linb1   = (const float*)d_in[19];
    const int*   ei      = (const int*)d_in[20];
    const int*   batch   = (const int*)d_in[21];
    const int*   pool1   = (const int*)d_in[22];
    const int*   eip     = (const int*)d_in[23];
    float* outp = (float*)d_out;

    // carve workspace (256B-aligned); zero-init block FIRST (single memset)
    char* p = (char*)d_ws;
    auto carve = [&](size_t bytes) -> void* {
        void* r = (void*)p;
        p += (bytes + 255) & ~(size_t)255;
        return r;
    };
    int*   deg    = (int*)  carve((size_t)NALL * 4);   // zeroed
    size_t zeroBytes = (size_t)((char*)p - (char*)deg);

    int*   rp     = (int*)  carve((size_t)(NALL + 1) * 4);
    int*   rpf    = (int*)  carve((size_t)(NALL + 1) * 4);
    float* dinv   = (float*)carve((size_t)NALL * 4);
    int*   blkSum = (int*)  carve(256 * 4);
    int*   blkOff = (int*)  carve(256 * 4);
    unsigned* csw = (unsigned*)carve((size_t)EALL * 4);
    unsigned short* rank = (unsigned short*)carve((size_t)EALL * 2);
    // region1: [xbf | z0bf] aliased later by g1bf (15.36 MB total)
    unsigned short* xbf  = (unsigned short*)carve((size_t)N0c * 256 * 2);
    unsigned short* z0bf = xbf + (size_t)N0c * 128;
    unsigned short* g1bf = xbf;                         // alias (xbf,z0bf dead)
    // region2: [g0bf | z1bf] aliased later by bufA (30.72 MB total)
    unsigned short* g0bf = (unsigned short*)carve((size_t)N0c * 256 * 4);
    unsigned short* z1bf = g0bf + (size_t)N0c * 256;
    float* bufA = (float*)g0bf;                         // alias (g0bf,z1bf dead)

    unsigned short* Wt0 = (unsigned short*)carve((size_t)256 * 128 * 2);
    unsigned short* Wt1 = (unsigned short*)carve((size_t)256 * 256 * 2);
    float* sc0 = (float*)carve(256 * 4);
    float* sh0 = (float*)carve(256 * 4);
    float* sc1 = (float*)carve(256 * 4);
    float* sh1 = (float*)carve(256 * 4);

    int*   start0 = (int*)  carve((size_t)(N1c + 1) * 4);
    int*   cnt0   = (int*)  carve((size_t)N1c * 4);
    float* pmean  = (float*)carve((size_t)N1c * 256 * 4);
    float* xp     = (float*)carve((size_t)N1c * 256 * 4);
    float* xb     = (float*)carve((size_t)N1c * 17 * 4);
    int*   bpool  = (int*)  carve((size_t)N1c * 4);
    unsigned short* hbbbf = (unsigned short*)carve((size_t)N1c * 256 * 2);
    float* zbb    = (float*)carve((size_t)N1c * 256 * 4);
    float* part   = (float*)carve((size_t)256 * 256 * 4);
    int*   pcnt   = (int*)  carve((size_t)256 * 4);

    hipMemsetAsync(deg, 0, zeroBytes, stream);

    const int* src0 = ei;
    const int* dst0 = ei + E0c;
    const int* src1 = eip;
    const int* dst1 = eip + E1c;

    // ---- CSR build: rank-in-count pass, atomic-free fill (4 dispatches) ----
    prep1<<<P1_E + P1_CVT + P1_PW + P1_SEG, 256, 0, stream>>>(
        dst0, dst1, deg, rank, x, xbf, W_in0, W_h0, b0, g0, be0, m0, v0,
        Wt0, Wt1, sc0, sh0, sc1, sh1, pool1, start0);
    int nb = cdiv_i(NALL, 256);
    scan_block<<<nb, 256, 0, stream>>>(deg, NALL, rp, blkSum, dinv);
    scan_sums<<<1, 256, 0, stream>>>(blkSum, nb, blkOff, rp, NALL);
    prep2<<<P2_FILL + P2_RPF, 256, 0, stream>>>(
        src0, dst0, src1, dst1, rp, blkOff, rank, dinv, csw, rpf);

    const int*   rp1   = rpf + N0c;
    const float* dinv1 = dinv + N0c;

    // ---- phase A: 3 GCN layers on N0 (layers 0/1: bf16 MFMA path) ----
    agg_bf16<16, 2, true><<<2 * cdiv_i(N0c, 8), 256, 0, stream>>>(xbf, rpf, csw, dinv, z0bf, N0c);
    gemm_mfma_bn<128><<<cdiv_i(N0c, 64), 256, 0, stream>>>(z0bf, Wt0, sc0, sh0, g0bf, N0c);
    agg_bf16<32, 4, true><<<4 * cdiv_i(N0c, 8), 256, 0, stream>>>(g0bf, rpf, csw, dinv, z1bf, N0c);
    gemm_mfma_bn<256><<<cdiv_i(N0c, 64), 256, 0, stream>>>(z1bf, Wt1, sc1, sh1, g1bf, N0c);
    agg_bf16<32, 4, false><<<4 * cdiv_i(N0c, 8), 256, 0, stream>>>(g1bf, rpf, csw, dinv, bufA, N0c);

    // layer 2: pool BEFORE GEMM (affine reorder); fp32 vector GEMM (precision)
    pool_mean<<<N1c, 64, 0, stream>>>(bufA, start0, batch, pmean, cnt0, bpool);
    gemm_bn<256, false, true, false><<<dim3(cdiv_i(N1c, 64), 4), 256, 0, stream>>>(
        pmean, W_h0 + Hc * Hc, b0 + 2 * Hc, g0 + 2 * Hc, be0 + 2 * Hc, m0 + 2 * Hc,
        v0 + 2 * Hc, cnt0, xp, N1c);

    // head0: logits + softmax -> d_out[0:48000], xb = [x0 | x_pool1]
    head0<<<N1c, 64, 0, stream>>>(xp, linW0, linb0, x_pool1, outp, xb);

    // ---- phase B: 3 GCN layers on N1 (fp32 vector GEMMs) ----
    agg17_gemm_bn<<<N1c, 256, 0, stream>>>(xb, rp1, csw, dinv1, W_in1, b1, g1, be1,
                                           m1, v1, hbbbf);
    agg_bf16<32, 4, false><<<4 * cdiv_i(N1c, 8), 256, 0, stream>>>(hbbbf, rp1, csw, dinv1, zbb, N1c);
    gemm_bn<256, true, false, true><<<dim3(cdiv_i(N1c, 64), 4), 256, 0, stream>>>(
        zbb, W_h1, b1 + Hc, g1 + Hc, be1 + Hc, m1 + Hc, v1 + Hc, nullptr, hbbbf, N1c);
    agg_bf16<32, 4, false><<<4 * cdiv_i(N1c, 8), 256, 0, stream>>>(hbbbf, rp1, csw, dinv1, zbb, N1c);

    // atomic-free 3000->16 reduction: 256-block partials, then head1 combines
    pool_b_partial<<<256, 256, 0, stream>>>(zbb, bpool, part, pcnt);
    head1<<<Bc, 256, 0, stream>>>(part, pcnt, W_h1 + Hc * Hc, b1 + 2 * Hc, g1 + 2 * Hc,
                                  be1 + 2 * Hc, m1 + 2 * Hc, v1 + 2 * Hc, linW1, linb1,
                                  outp);
}

// Round 15
// 443.605 us; speedup vs baseline: 1.4944x; 1.0025x over previous
//
#include <hip/hip_runtime.h>
#include <cstdint>
#include <cstddef>

// Problem constants
#define N0c 30000
#define F0c 128
#define Hc  256
#define Cc  16
#define N1c 3000
#define Bc  16
#define E0c 960000
#define E1c 48000
#define NALL 33000            // N0 + N1 (concatenated graphs)
#define EALL 1008000          // E0 + E1
#define EPSc 1e-5f
#define SLICE 188             // clusters per pool_b_partial slice (16*188 >= 3000)
#define NPART 8               // histogram partitions (breaks atomic line serialization)

static __host__ __device__ inline int cdiv_i(int a, int b) { return (a + b - 1) / b; }

// round-to-nearest-even fp32 -> bf16 (returns the 16 bf16 bits)
static __device__ inline unsigned short bfbits(float f) {
    unsigned u = __float_as_uint(f);
    return (unsigned short)((u + 0x7fffu + ((u >> 16) & 1u)) >> 16);
}

typedef short short8 __attribute__((ext_vector_type(8)));   // 8 bf16 = 4 VGPRs
typedef float floatx4 __attribute__((ext_vector_type(4)));

// ---------------- prep1: partitioned degree+rank histogram + indep work -------
// r15: histogram split into NPART partitions (p = blockIdx&7) -> 8x more cache
// lines -> memory-side RMW serialization /8 (r14 post-mortem: 1M atomics on
// 2062 lines ~ 40us). rank[e] = within-partition rank; partition recoverable
// in prep2 as (e>>8)&7. Final rank = pptab[d][p] (per-node prefix) + rank[e].
#define P1_E   3938
#define P1_CVT 3750
#define P1_PW  386
#define P1_SEG 118

__global__ void prep1(const int* __restrict__ dst0, const int* __restrict__ dst1,
                      int* __restrict__ deg_part, unsigned short* __restrict__ rank,
                      const float* __restrict__ x, unsigned short* __restrict__ xbf,
                      const float* __restrict__ W_in0, const float* __restrict__ W_h0,
                      const float* __restrict__ b0, const float* __restrict__ g0,
                      const float* __restrict__ be0, const float* __restrict__ m0,
                      const float* __restrict__ v0,
                      unsigned short* __restrict__ Wt0, unsigned short* __restrict__ Wt1,
                      float* __restrict__ sc0, float* __restrict__ sh0,
                      float* __restrict__ sc1, float* __restrict__ sh1,
                      const int* __restrict__ pool1, int* __restrict__ start0) {
    int bx = blockIdx.x, t = threadIdx.x;
    if (bx < P1_E) {
        int e = bx * 256 + t;
        if (e >= EALL) return;
        int d = (e < E0c) ? dst0[e] : (N0c + dst1[e - E0c]);
        int p = bx & (NPART - 1);
        rank[e] = (unsigned short)atomicAdd(&deg_part[p * NALL + d], 1);
    } else if (bx < P1_E + P1_CVT) {
        int i = (bx - P1_E) * 256 + t;              // float4 index
        if (i >= N0c * 32) return;
        float4 v = ((const float4*)x)[i];
        ushort4 o;
        o.x = bfbits(v.x); o.y = bfbits(v.y); o.z = bfbits(v.z); o.w = bfbits(v.w);
        ((ushort4*)xbf)[i] = o;
    } else if (bx < P1_E + P1_CVT + P1_PW) {
        int pb = bx - P1_E - P1_CVT;
        if (pb < 128) {
            int i = pb * 256 + t;
            int k = i >> 8, col = i & 255;
            Wt0[col * 128 + k] = bfbits(W_in0[i]);
        } else if (pb < 384) {
            int i = (pb - 128) * 256 + t;
            int k = i >> 8, col = i & 255;
            Wt1[col * 256 + k] = bfbits(W_h0[i]);
        } else if (pb == 384) {
            float s = g0[t] * rsqrtf(v0[t] + EPSc);
            sc0[t] = s;
            sh0[t] = (b0[t] - m0[t]) * s + be0[t];
        } else {
            int tt = t + 256;
            float s = g0[tt] * rsqrtf(v0[tt] + EPSc);
            sc1[t] = s;
            sh1[t] = (b0[tt] - m0[tt]) * s + be0[tt];
        }
    } else {
        int i = (bx - P1_E - P1_CVT - P1_PW) * 256 + t;
        if (i > N0c) return;
        if (i == 0) {
            for (int c = 0; c <= pool1[0]; ++c) start0[c] = 0;
        } else if (i == N0c) {
            for (int c = pool1[N0c - 1] + 1; c <= N1c; ++c) start0[c] = N0c;
        } else {
            int a = pool1[i - 1], b = pool1[i];
            for (int c = a + 1; c <= b; ++c) start0[c] = i;
        }
    }
}

// scan + dinv + partition-prefix fused: sums the 8 partition counts per node,
// computes dinv = rsqrt(deg+1), per-node exclusive prefix pptab[i][p] (u16x8),
// and the block-level exclusive scan of total degree.
__global__ void scan_block(const int* __restrict__ deg_part, int n, int* __restrict__ rp,
                           int* __restrict__ blkSum, float* __restrict__ dinv,
                           unsigned short* __restrict__ pptab) {
    __shared__ int sh[256];
    int t = threadIdx.x;
    int i = blockIdx.x * 256 + t;
    int v = 0;
    if (i < n) {
        unsigned short pp[NPART];
        int run = 0;
#pragma unroll
        for (int p = 0; p < NPART; ++p) {
            pp[p] = (unsigned short)run;
            run += deg_part[p * NALL + i];
        }
        v = run;
        dinv[i] = rsqrtf((float)(v + 1));
        *(uint4*)&pptab[(size_t)i * NPART] = *(const uint4*)pp;
    }
    sh[t] = v; __syncthreads();
    for (int off = 1; off < 256; off <<= 1) {
        int add = (t >= off) ? sh[t - off] : 0;
        __syncthreads();
        sh[t] += add;
        __syncthreads();
    }
    if (i < n) rp[i] = sh[t] - v;
    if (t == 255) blkSum[blockIdx.x] = sh[255];
}

__global__ void scan_sums(const int* __restrict__ blkSum, int nb, int* __restrict__ blkOff,
                          int* __restrict__ rp, int n) {
    __shared__ int sh[256];
    int t = threadIdx.x;
    int v = (t < nb) ? blkSum[t] : 0;
    sh[t] = v; __syncthreads();
    for (int off = 1; off < 256; off <<= 1) {
        int add = (t >= off) ? sh[t - off] : 0;
        __syncthreads();
        sh[t] += add;
        __syncthreads();
    }
    blkOff[t] = sh[t] - v;
    if (t == 255) rp[n] = sh[255];
}

// ---------------- prep2: ATOMIC-FREE csr fill + final row pointers ------------
#define P2_FILL 3938
#define P2_RPF  129

__global__ void prep2(const int* __restrict__ src0, const int* __restrict__ dst0,
                      const int* __restrict__ src1, const int* __restrict__ dst1,
                      const int* __restrict__ rp, const int* __restrict__ blkOff,
                      const unsigned short* __restrict__ rank,
                      const unsigned short* __restrict__ pptab,
                      const float* __restrict__ dinv, unsigned* __restrict__ csw,
                      int* __restrict__ rpf) {
    int bx = blockIdx.x, t = threadIdx.x;
    if (bx < P2_FILL) {
        int e = bx * 256 + t;
        if (e >= EALL) return;
        int s, d;
        if (e < E0c) { s = src0[e]; d = dst0[e]; }
        else         { s = N0c + src1[e - E0c]; d = N0c + dst1[e - E0c]; }
        int p = bx & (NPART - 1);    // same partition mapping as prep1
        int pos = rp[d] + blkOff[d >> 8] + (int)pptab[(size_t)d * NPART + p] + (int)rank[e];
        float w = dinv[s] * dinv[d];
        int sloc = (e < E0c) ? s : (s - N0c);
        csw[pos] = ((unsigned)bfbits(w) << 16) | (unsigned)sloc;
    } else {
        int i = (bx - P2_FILL) * 256 + t;
        if (i < NALL) rpf[i] = rp[i] + blkOff[i >> 8];
        else if (i == NALL) rpf[NALL] = rp[NALL];   // total (already final)
    }
}

// ---------------- aggregation (bf16 gather, fp32 accumulate) ----------------

static __device__ inline void acc8(float a[8], float w, uint4 v) {
    a[0] += w * __uint_as_float(v.x << 16);
    a[1] += w * __uint_as_float(v.x & 0xffff0000u);
    a[2] += w * __uint_as_float(v.y << 16);
    a[3] += w * __uint_as_float(v.y & 0xffff0000u);
    a[4] += w * __uint_as_float(v.z << 16);
    a[5] += w * __uint_as_float(v.z & 0xffff0000u);
    a[6] += w * __uint_as_float(v.w << 16);
    a[7] += w * __uint_as_float(v.w & 0xffff0000u);
}

// TWO nodes per wave, FOUR edge slots each (lane = ns*32 + par*8 + cl).
// NCHUNK chunks of 64 cols; chunk = blockIdx&(NCHUNK-1) keeps XCD pinning.
// 32-bit gather addressing; wave-uniform (max-over-pair) trip counts; unroll-2.
template <int RSU, int NCHUNK, bool OBF16>
__global__ __launch_bounds__(256) void agg_bf16(
    const unsigned short* __restrict__ x, const int* __restrict__ rp,
    const unsigned* __restrict__ csw, const float* __restrict__ dinv,
    void* __restrict__ zv, int N) {
    constexpr int SHIFT = (RSU == 32) ? 9 : 8;   // log2(row bytes)
    int b = blockIdx.x;
    int chunk = b & (NCHUNK - 1);
    int wave = threadIdx.x >> 6;
    int lane = threadIdx.x & 63;
    int ns = lane >> 5;                  // node sub (0/1)
    int par = (lane >> 3) & 3;           // edge slot (0..3)
    int cl = lane & 7;                   // 16B slice within 64-col chunk
    int node = (b / NCHUNK) * 8 + wave * 2 + ns;
    bool valid = node < N;
    int nclamp = valid ? node : 0;
    int c4 = chunk * 8 + cl;
    unsigned coff = (unsigned)c4 << 4;
    const char* xb = (const char*)x;
    float a[8] = {0.f, 0.f, 0.f, 0.f, 0.f, 0.f, 0.f, 0.f};
    int e0 = rp[nclamp];
    int e1 = valid ? rp[nclamp + 1] : e0;
    if (valid && par == 0) {             // self-loop term exactly once
        float di = dinv[node];
        uint4 v = *(const uint4*)(xb + (((unsigned)node << SHIFT) + coff));
        acc8(a, di * di, v);
    }
    int deg = e1 - e0;
    int myw = (deg + 31) >> 5;
    int nwin = max(__shfl(myw, 0, 64), __shfl(myw, 32, 64));   // wave-uniform
    int srcbase = lane & 32;
    for (int w = 0; w < nwin; ++w) {
        int base = e0 + w * 32;
        int avail = e1 - base;
        int cnt = avail < 0 ? 0 : (avail > 32 ? 32 : avail);   // per-half count
        unsigned my = 0;
        int li = lane & 31;
        if (li < cnt) my = csw[base + li];   // 32 edges per half in ONE load
        int mysteps = (cnt + 3) >> 2;
        int steps = max(__shfl(mysteps, 0, 64), __shfl(mysteps, 32, 64));
        int i = 0;
        for (; i + 1 < steps; i += 2) {      // 2 gathers in flight per half
            int idx0 = i * 4 + par, idx1 = idx0 + 4;
            unsigned ew0 = (unsigned)__shfl((int)my, srcbase + idx0, 64);
            unsigned ew1 = (unsigned)__shfl((int)my, srcbase + idx1, 64);
            if (idx0 < cnt) {
                uint4 v = *(const uint4*)(xb + (((ew0 & 0xffffu) << SHIFT) + coff));
                acc8(a, __uint_as_float(ew0 & 0xffff0000u), v);
            }
            if (idx1 < cnt) {
                uint4 v = *(const uint4*)(xb + (((ew1 & 0xffffu) << SHIFT) + coff));
                acc8(a, __uint_as_float(ew1 & 0xffff0000u), v);
            }
        }
        if (i < steps) {
            int idx = i * 4 + par;
            unsigned ew = (unsigned)__shfl((int)my, srcbase + idx, 64);
            if (idx < cnt) {
                uint4 v = *(const uint4*)(xb + (((ew & 0xffffu) << SHIFT) + coff));
                acc8(a, __uint_as_float(ew & 0xffff0000u), v);
            }
        }
    }
    // reduce across the 4 edge slots (2 levels, stays within each node half)
#pragma unroll
    for (int m = 8; m < 32; m <<= 1) {
#pragma unroll
        for (int k = 0; k < 8; ++k) a[k] += __shfl_xor(a[k], m, 64);
    }
    if (valid && par == 0) {
        if (OBF16) {
            uint4 o;
            o.x = (unsigned)bfbits(a[0]) | ((unsigned)bfbits(a[1]) << 16);
            o.y = (unsigned)bfbits(a[2]) | ((unsigned)bfbits(a[3]) << 16);
            o.z = (unsigned)bfbits(a[4]) | ((unsigned)bfbits(a[5]) << 16);
            o.w = (unsigned)bfbits(a[6]) | ((unsigned)bfbits(a[7]) << 16);
            ((uint4*)zv)[(size_t)node * RSU + c4] = o;
        } else {
            float4* zp = (float4*)zv + (size_t)node * (RSU * 2) + c4 * 2;
            zp[0] = make_float4(a[0], a[1], a[2], a[3]);
            zp[1] = make_float4(a[4], a[5], a[6], a[7]);
        }
    }
}

// ---------------- MFMA bf16 GEMM: (M x K)bf16 @ Wt(256 x K)bf16 -> bf16 out ----

template <int K>
__global__ __launch_bounds__(256) void gemm_mfma_bn(
    const unsigned short* __restrict__ A, const unsigned short* __restrict__ Wt,
    const float* __restrict__ sc, const float* __restrict__ sh,
    unsigned short* __restrict__ out, int M) {
    constexpr int LDS_S = 40;
    __shared__ unsigned short As[64 * LDS_S];
    __shared__ unsigned short Bs[256 * LDS_S];
    int tid = threadIdx.x;
    int w = tid >> 6, l = tid & 63;
    int quad = l >> 4, lm = l & 15;
    int row0 = blockIdx.x * 64;
    floatx4 acc[4][4];
#pragma unroll
    for (int i = 0; i < 4; ++i)
#pragma unroll
        for (int j = 0; j < 4; ++j) acc[i][j] = (floatx4){0.f, 0.f, 0.f, 0.f};

    int ar = tid >> 2;          // A staging: row 0..63
    int ac = (tid & 3) * 8;     // short offset 0,8,16,24

    for (int k0 = 0; k0 < K; k0 += 32) {
        uint4 av = make_uint4(0, 0, 0, 0);
        if (row0 + ar < M) av = *(const uint4*)(A + (size_t)(row0 + ar) * K + k0 + ac);
        *(uint4*)&As[ar * LDS_S + ac] = av;
#pragma unroll
        for (int c = 0; c < 4; ++c) {    // Bs: thread -> col tid, 4 k-chunks
            uint4 bv = *(const uint4*)(Wt + (size_t)tid * K + k0 + c * 8);
            *(uint4*)&Bs[tid * LDS_S + c * 8] = bv;
        }
        __syncthreads();
        short8 af[4], bf[4];
#pragma unroll
        for (int i = 0; i < 4; ++i)
            af[i] = *(const short8*)&As[(i * 16 + lm) * LDS_S + quad * 8];
#pragma unroll
        for (int j = 0; j < 4; ++j)
            bf[j] = *(const short8*)&Bs[(w * 64 + j * 16 + lm) * LDS_S + quad * 8];
#pragma unroll
        for (int i = 0; i < 4; ++i)
#pragma unroll
            for (int j = 0; j < 4; ++j)
                acc[i][j] = __builtin_amdgcn_mfma_f32_16x16x32_bf16(af[i], bf[j], acc[i][j], 0, 0, 0);
        __syncthreads();
    }
    // epilogue: C/D map col=lane&15, row=quad*4+reg [verified m89/m91]
#pragma unroll
    for (int j = 0; j < 4; ++j) {
        int col = w * 64 + j * 16 + lm;
        float s = sc[col], h = sh[col];
#pragma unroll
        for (int i = 0; i < 4; ++i) {
            int rb = row0 + i * 16 + quad * 4;
#pragma unroll
            for (int r = 0; r < 4; ++r) {
                int row = rb + r;
                if (row < M) {
                    float v = acc[i][j][r] * s + h;
                    v = fmaxf(v, 0.f);
                    out[(size_t)row * 256 + col] = bfbits(v);
                }
            }
        }
    }
}

// ---------------- fp32 vector GEMM (kept for small M=3000, precision-critical) --

template <int K, bool RELU, bool ZEROEMPTY, bool OBF16>
__global__ __launch_bounds__(256) void gemm_bn(
    const float* __restrict__ A, const float* __restrict__ W,
    const float* __restrict__ bias, const float* __restrict__ gam,
    const float* __restrict__ bet, const float* __restrict__ mu,
    const float* __restrict__ var, const int* __restrict__ cnt,
    void* __restrict__ outv, int M) {
    __shared__ __align__(16) float As[16][64];
    __shared__ __align__(16) float Bs[16][64];
    int tid = threadIdx.x;
    int tm = tid >> 4, tn = tid & 15;
    int row0 = blockIdx.x * 64, col0 = blockIdx.y * 64;
    float acc[4][4] = {};
    int ar = tid >> 2;
    int ak = (tid & 3) * 4;
    int bk = tid >> 4;
    int bn = (tid & 15) * 4;

    for (int kk = 0; kk < K; kk += 16) {
        float4 av = make_float4(0.f, 0.f, 0.f, 0.f);
        int grow = row0 + ar;
        if (grow < M) av = *(const float4*)(A + (size_t)grow * K + kk + ak);
        As[ak + 0][ar] = av.x;
        As[ak + 1][ar] = av.y;
        As[ak + 2][ar] = av.z;
        As[ak + 3][ar] = av.w;
        float4 bv = *(const float4*)(W + (size_t)(kk + bk) * 256 + col0 + bn);
        *(float4*)&Bs[bk][bn] = bv;
        __syncthreads();
#pragma unroll
        for (int k = 0; k < 16; ++k) {
            float4 a = *(const float4*)&As[k][tm * 4];
            float4 b = *(const float4*)&Bs[k][tn * 4];
            acc[0][0] += a.x * b.x; acc[0][1] += a.x * b.y; acc[0][2] += a.x * b.z; acc[0][3] += a.x * b.w;
            acc[1][0] += a.y * b.x; acc[1][1] += a.y * b.y; acc[1][2] += a.y * b.z; acc[1][3] += a.y * b.w;
            acc[2][0] += a.z * b.x; acc[2][1] += a.z * b.y; acc[2][2] += a.z * b.z; acc[2][3] += a.z * b.w;
            acc[3][0] += a.w * b.x; acc[3][1] += a.w * b.y; acc[3][2] += a.w * b.z; acc[3][3] += a.w * b.w;
        }
        __syncthreads();
    }
    float bcol[4], scol[4], mcol[4], ecol[4];
#pragma unroll
    for (int j = 0; j < 4; ++j) {
        int col = col0 + tn * 4 + j;
        bcol[j] = bias[col];
        scol[j] = gam[col] * rsqrtf(var[col] + EPSc);
        mcol[j] = mu[col];
        ecol[j] = bet[col];
    }
#pragma unroll
    for (int i = 0; i < 4; ++i) {
        int row = row0 + tm * 4 + i;
        if (row >= M) continue;
        bool zero = false;
        if (ZEROEMPTY) zero = (cnt[row] == 0);
        float r[4];
#pragma unroll
        for (int j = 0; j < 4; ++j) {
            float v = acc[i][j] + bcol[j];
            v = (v - mcol[j]) * scol[j] + ecol[j];
            if (RELU) v = fmaxf(v, 0.f);
            if (zero) v = 0.f;
            r[j] = v;
        }
        if (OBF16) {
            ushort4 o;
            o.x = bfbits(r[0]); o.y = bfbits(r[1]); o.z = bfbits(r[2]); o.w = bfbits(r[3]);
            *(ushort4*)((unsigned short*)outv + (size_t)row * 256 + col0 + tn * 4) = o;
        } else {
            float4 o = make_float4(r[0], r[1], r[2], r[3]);
            *(float4*)((float*)outv + (size_t)row * 256 + col0 + tn * 4) = o;
        }
    }
}

// fused: 17-wide aggregation (graph 1) + K=17 GEMM + BN + ReLU, bf16 out
__global__ void agg17_gemm_bn(const float* __restrict__ xb, const int* __restrict__ rp,
                              const unsigned* __restrict__ csw, const float* __restrict__ dinv,
                              const float* __restrict__ W, const float* __restrict__ bias,
                              const float* __restrict__ gam, const float* __restrict__ bet,
                              const float* __restrict__ mu, const float* __restrict__ var,
                              unsigned short* __restrict__ out) {
    int r = blockIdx.x, t = threadIdx.x;   // 256 threads
    __shared__ float zr[17];
    if (t < 17) {
        float di = dinv[r];
        float acc = di * di * xb[(size_t)r * 17 + t];
        int e0 = rp[r], e1 = rp[r + 1];
        for (int e = e0; e < e1; ++e) {
            unsigned ew = csw[e];
            acc += __uint_as_float(ew & 0xffff0000u) * xb[(size_t)(ew & 0xffffu) * 17 + t];
        }
        zr[t] = acc;
    }
    __syncthreads();
    float acc = bias[t];
#pragma unroll
    for (int k = 0; k < 17; ++k) acc += zr[k] * W[k * 256 + t];
    float s = gam[t] * rsqrtf(var[t] + EPSc);
    acc = (acc - mu[t]) * s + bet[t];
    acc = fmaxf(acc, 0.f);
    out[(size_t)r * 256 + t] = bfbits(acc);
}

// ---------------- pooling ----------------

__global__ void pool_mean(const float* __restrict__ z, const int* __restrict__ start,
                          const int* __restrict__ batch, float* __restrict__ p,
                          int* __restrict__ cnt_out, int* __restrict__ bpool) {
    int c = blockIdx.x, t = threadIdx.x;  // 64 threads
    int s = start[c], e = start[c + 1];
    int cnt = e - s;
    const float4* z4 = (const float4*)z;
    float ax = 0.f, ay = 0.f, az = 0.f, aw = 0.f;
    for (int i = s; i < e; ++i) {
        float4 v = z4[(size_t)i * 64 + t];
        ax += v.x; ay += v.y; az += v.z; aw += v.w;
    }
    float inv = 1.0f / (float)max(cnt, 1);
    ((float4*)p)[(size_t)c * 64 + t] = make_float4(ax * inv, ay * inv, az * inv, aw * inv);
    if (t == 0) {
        cnt_out[c] = cnt;
        int sb = 0;
        for (int i = s; i < e; ++i) sb += batch[i];
        bpool[c] = (int)rintf((float)sb * inv);
    }
}

// stage 1 of atomic-free 3000->16 reduction: 256 blocks = 16 graphs x 16 slices.
__global__ __launch_bounds__(256) void pool_b_partial(
    const float* __restrict__ zbb, const int* __restrict__ bpool,
    float* __restrict__ part, int* __restrict__ pcnt) {
    int b = blockIdx.x;          // 0..255
    int g = b & 15, s = b >> 4;
    int t = threadIdx.x;
    int i0 = s * SLICE;
    int n = min(N1c - i0, SLICE);
    __shared__ int bp[SLICE];
    for (int i = t; i < n; i += 256) bp[i] = bpool[i0 + i];
    __syncthreads();
    float acc = 0.f;
    int c = 0;
    for (int i = 0; i < n; ++i) {
        int hit = (bp[i] == g);
        float sel = hit ? 1.f : 0.f;
        acc += sel * zbb[(size_t)(i0 + i) * 256 + t];   // load NOT branch-gated
        c += hit;
    }
    part[(size_t)b * 256 + t] = acc;
    if (t == 0) pcnt[b] = c;
}

// ---------------- heads ----------------

__global__ void head0(const float* __restrict__ xp, const float* __restrict__ linW,
                      const float* __restrict__ linb, const float* __restrict__ xpool1,
                      float* __restrict__ outp, float* __restrict__ xb) {
    int r = blockIdx.x, t = threadIdx.x;  // 64 threads
    __shared__ float xr[256];
    __shared__ float lg[16];
    __shared__ float ex[16];
#pragma unroll
    for (int j = 0; j < 4; ++j) xr[t + 64 * j] = xp[(size_t)r * 256 + t + 64 * j];
    __syncthreads();
    if (t < 16) {
        float acc = linb[t];
        for (int k = 0; k < 256; ++k) acc += xr[k] * linW[k * 16 + t];
        lg[t] = acc;
    }
    __syncthreads();
    if (t < 16) {
        float mx = lg[0];
#pragma unroll
        for (int c = 1; c < 16; ++c) mx = fmaxf(mx, lg[c]);
        ex[t] = expf(lg[t] - mx);
    }
    __syncthreads();
    if (t < 16) {
        float sum = 0.f;
#pragma unroll
        for (int c = 0; c < 16; ++c) sum += ex[c];
        float pv = ex[t] / sum;
        outp[(size_t)r * 16 + t] = pv;
        xb[(size_t)r * 17 + t] = pv;
    }
    if (t == 16) xb[(size_t)r * 17 + 16] = xpool1[r];
}

// head1: sum 16 partials -> mean -> layer2 GEMM+BN -> logits -> softmax
__global__ void head1(const float* __restrict__ part, const int* __restrict__ pcnt,
                      const float* __restrict__ W, const float* __restrict__ bias,
                      const float* __restrict__ gam, const float* __restrict__ bet,
                      const float* __restrict__ mu, const float* __restrict__ var,
                      const float* __restrict__ linW, const float* __restrict__ linb,
                      float* __restrict__ outp) {
    int b = blockIdx.x, t = threadIdx.x;  // 16 blocks x 256 threads
    __shared__ float pr[256];
    __shared__ float yr[256];
    __shared__ float lg[16];
    __shared__ float ex[16];
    float acc0 = 0.f;
    int c = 0;
#pragma unroll
    for (int s = 0; s < 16; ++s) {
        int pb = s * 16 + b;
        acc0 += part[(size_t)pb * 256 + t];
        c += pcnt[pb];
    }
    float inv = 1.0f / (float)max(c, 1);
    pr[t] = acc0 * inv;
    __syncthreads();
    float acc = bias[t];
    for (int k = 0; k < 256; ++k) acc += pr[k] * W[k * 256 + t];
    float s = gam[t] * rsqrtf(var[t] + EPSc);
    acc = (acc - mu[t]) * s + bet[t];
    if (c == 0) acc = 0.f;
    yr[t] = acc;
    __syncthreads();
    if (t < 16) {
        float l = linb[t];
        for (int k = 0; k < 256; ++k) l += yr[k] * linW[k * 16 + t];
        lg[t] = l;
    }
    __syncthreads();
    if (t < 16) {
        float mx = lg[0];
#pragma unroll
        for (int cc = 1; cc < 16; ++cc) mx = fmaxf(mx, lg[cc]);
        ex[t] = expf(lg[t] - mx);
    }
    __syncthreads();
    if (t < 16) {
        float sum = 0.f;
#pragma unroll
        for (int cc = 0; cc < 16; ++cc) sum += ex[cc];
        outp[48000 + b * 16 + t] = ex[t] / sum;
    }
}

// ---------------- launch ----------------

extern "C" void kernel_launch(void* const* d_in, const int* in_sizes, int n_in,
                              void* d_out, int out_size, void* d_ws, size_t ws_size,
                              hipStream_t stream) {
    const float* x       = (const float*)d_in[0];
    const float* x_pool1 = (const float*)d_in[1];
    const float* W_in0   = (const float*)d_in[2];
    const float* W_h0    = (const float*)d_in[3];
    const float* b0      = (const float*)d_in[4];
    const float* g0      = (const float*)d_in[5];
    const float* be0     = (const float*)d_in[6];
    const float* m0      = (const float*)d_in[7];
    const float* v0      = (const float*)d_in[8];
    const float* W_in1   = (const float*)d_in[9];
    const float* W_h1    = (const float*)d_in[10];
    const float* b1      = (const float*)d_in[11];
    const float* g1      = (const float*)d_in[12];
    const float* be1     = (const float*)d_in[13];
    const float* m1      = (const float*)d_in[14];
    const float* v1      = (const float*)d_in[15];
    const float* linW0   = (const float*)d_in[16];
    const float* linb0   = (const float*)d_in[17];
    const float* linW1   = (const float*)d_in[18];
    const float* linb1   = (const float*)d_in[19];
    const int*   ei      = (const int*)d_in[20];
    const int*   batch   = (const int*)d_in[21];
    const int*   pool1   = (const int*)d_in[22];
    const int*   eip     = (const int*)d_in[23];
    float* outp = (float*)d_out;

    // carve workspace (256B-aligned); zero-init block FIRST (single memset)
    char* p = (char*)d_ws;
    auto carve = [&](size_t bytes) -> void* {
        void* r = (void*)p;
        p += (bytes + 255) & ~(size_t)255;
        return r;
    };
    int* deg_part = (int*)carve((size_t)NPART * NALL * 4);  // zeroed
    size_t zeroBytes = (size_t)((char*)p - (char*)deg_part);

    int*   rp     = (int*)  carve((size_t)(NALL + 1) * 4);
    int*   rpf    = (int*)  carve((size_t)(NALL + 1) * 4);
    float* dinv   = (float*)carve((size_t)NALL * 4);
    int*   blkSum = (int*)  carve(256 * 4);
    int*   blkOff = (int*)  carve(256 * 4);
    unsigned* csw = (unsigned*)carve((size_t)EALL * 4);
    unsigned short* rank  = (unsigned short*)carve((size_t)EALL * 2);
    unsigned short* pptab = (unsigned short*)carve((size_t)NALL * NPART * 2);
    // region1: [xbf | z0bf] aliased later by g1bf (15.36 MB total)
    unsigned short* xbf  = (unsigned short*)carve((size_t)N0c * 256 * 2);
    unsigned short* z0bf = xbf + (size_t)N0c * 128;
    unsigned short* g1bf = xbf;                         // alias (xbf,z0bf dead)
    // region2: [g0bf | z1bf] aliased later by bufA (30.72 MB total)
    unsigned short* g0bf = (unsigned short*)carve((size_t)N0c * 256 * 4);
    unsigned short* z1bf = g0bf + (size_t)N0c * 256;
    float* bufA = (float*)g0bf;                         // alias (g0bf,z1bf dead)

    unsigned short* Wt0 = (unsigned short*)carve((size_t)256 * 128 * 2);
    unsigned short* Wt1 = (unsigned short*)carve((size_t)256 * 256 * 2);
    float* sc0 = (float*)carve(256 * 4);
    float* sh0 = (float*)carve(256 * 4);
    float* sc1 = (float*)carve(256 * 4);
    float* sh1 = (float*)carve(256 * 4);

    int*   start0 = (int*)  carve((size_t)(N1c + 1) * 4);
    int*   cnt0   = (int*)  carve((size_t)N1c * 4);
    float* pmean  = (float*)carve((size_t)N1c * 256 * 4);
    float* xp     = (float*)carve((size_t)N1c * 256 * 4);
    float* xb     = (float*)carve((size_t)N1c * 17 * 4);
    int*   bpool  = (int*)  carve((size_t)N1c * 4);
    unsigned short* hbbbf = (unsigned short*)carve((size_t)N1c * 256 * 2);
    float* zbb    = (float*)carve((size_t)N1c * 256 * 4);
    float* part   = (float*)carve((size_t)256 * 256 * 4);
    int*   pcnt   = (int*)  carve((size_t)256 * 4);

    hipMemsetAsync(deg_part, 0, zeroBytes, stream);

    const int* src0 = ei;
    const int* dst0 = ei + E0c;
    const int* src1 = eip;
    const int* dst1 = eip + E1c;

    // ---- CSR build: partitioned rank histogram, atomic-free fill ----
    prep1<<<P1_E + P1_CVT + P1_PW + P1_SEG, 256, 0, stream>>>(
        dst0, dst1, deg_part, rank, x, xbf, W_in0, W_h0, b0, g0, be0, m0, v0,
        Wt0, Wt1, sc0, sh0, sc1, sh1, pool1, start0);
    int nb = cdiv_i(NALL, 256);
    scan_block<<<nb, 256, 0, stream>>>(deg_part, NALL, rp, blkSum, dinv, pptab);
    scan_sums<<<1, 256, 0, stream>>>(blkSum, nb, blkOff, rp, NALL);
    prep2<<<P2_FILL + P2_RPF, 256, 0, stream>>>(
        src0, dst0, src1, dst1, rp, blkOff, rank, pptab, dinv, csw, rpf);

    const int*   rp1   = rpf + N0c;
    const float* dinv1 = dinv + N0c;

    // ---- phase A: 3 GCN layers on N0 (layers 0/1: bf16 MFMA path) ----
    agg_bf16<16, 2, true><<<2 * cdiv_i(N0c, 8), 256, 0, stream>>>(xbf, rpf, csw, dinv, z0bf, N0c);
    gemm_mfma_bn<128><<<cdiv_i(N0c, 64), 256, 0, stream>>>(z0bf, Wt0, sc0, sh0, g0bf, N0c);
    agg_bf16<32, 4, true><<<4 * cdiv_i(N0c, 8), 256, 0, stream>>>(g0bf, rpf, csw, dinv, z1bf, N0c);
    gemm_mfma_bn<256><<<cdiv_i(N0c, 64), 256, 0, stream>>>(z1bf, Wt1, sc1, sh1, g1bf, N0c);
    agg_bf16<32, 4, false><<<4 * cdiv_i(N0c, 8), 256, 0, stream>>>(g1bf, rpf, csw, dinv, bufA, N0c);

    // layer 2: pool BEFORE GEMM (affine reorder); fp32 vector GEMM (precision)
    pool_mean<<<N1c, 64, 0, stream>>>(bufA, start0, batch, pmean, cnt0, bpool);
    gemm_bn<256, false, true, false><<<dim3(cdiv_i(N1c, 64), 4), 256, 0, stream>>>(
        pmean, W_h0 + Hc * Hc, b0 + 2 * Hc, g0 + 2 * Hc, be0 + 2 * Hc, m0 + 2 * Hc,
        v0 + 2 * Hc, cnt0, xp, N1c);

    // head0: logits + softmax -> d_out[0:48000], xb = [x0 | x_pool1]
    head0<<<N1c, 64, 0, stream>>>(xp, linW0, linb0, x_pool1, outp, xb);

    // ---- phase B: 3 GCN layers on N1 (fp32 vector GEMMs) ----
    agg17_gemm_bn<<<N1c, 256, 0, stream>>>(xb, rp1, csw, dinv1, W_in1, b1, g1, be1,
                                           m1, v1, hbbbf);
    agg_bf16<32, 4, false><<<4 * cdiv_i(N1c, 8), 256, 0, stream>>>(hbbbf, rp1, csw, dinv1, zbb, N1c);
    gemm_bn<256, true, false, true><<<dim3(cdiv_i(N1c, 64), 4), 256, 0, stream>>>(
        zbb, W_h1, b1 + Hc, g1 + Hc, be1 + Hc, m1 + Hc, v1 + Hc, nullptr, hbbbf, N1c);
    agg_bf16<32, 4, false><<<4 * cdiv_i(N1c, 8), 256, 0, stream>>>(hbbbf, rp1, csw, dinv1, zbb, N1c);

    // atomic-free 3000->16 reduction: 256-block partials, then head1 combines
    pool_b_partial<<<256, 256, 0, stream>>>(zbb, bpool, part, pcnt);
    head1<<<Bc, 256, 0, stream>>>(part, pcnt, W_h1 + Hc * Hc, b1 + 2 * Hc, g1 + 2 * Hc,
                                  be1 + 2 * Hc, m1 + 2 * Hc, v1 + 2 * Hc, linW1, linb1,
                                  outp);
}